// Round 8
// baseline (79964.941 us; speedup 1.0000x reference)
//
#include <hip/hip_runtime.h>
#include <hip/hip_bf16.h>

// QLSTM (S=512,B=256,D=256,H=256,E=512), f32 in/out, bf16 MFMA internals.
// 256 persistent WGs x 1024 threads; 2 flag-tree grid barriers per step.
//   A    : q,k,vT = [x_t|hx] @ [Wq|Wk|Wv]^T   (all WGs, 6 tiles each)
//   BCDE : scores->softmax->attn->gates->LSTM  (strip WGs wg<16)
// Data path: PLAIN cached wide loads/stores; release fence (wbl2) before
// arrival, acquire fence (inv) after release — no per-access sc1 storm.
// All waves busy-spin (dummy FMA) during barrier waits to hold clocks up.

typedef __hip_bfloat16 bf16;
typedef __attribute__((ext_vector_type(8))) short bf16x8;   // 8 bf16 = 4 VGPR
typedef __attribute__((ext_vector_type(4))) float f32x4;
typedef unsigned long long u64;

#define SEQ 512
#define BB  256
#define DD  256
#define HH  256
#define EE  512
#define NWG 256
#define QK_SCALE 0.04419417382415922f  // 1/sqrt(512)

// ws layout (bytes)
#define WS_Q     0          // bf16 [256][512]  batch-major
#define WS_K     262144     // bf16 [256][512]  batch-major
#define WS_VT    524288     // bf16 [512][256]  e-major (v transposed)
#define WS_HX    1048576    // bf16 [256][256]  batch-major
#define WS_WQ    1441792    // bf16 [512][512]
#define WS_WK    1966080    // bf16 [512][512]
#define WS_WV    2490368    // bf16 [512][512]
#define WS_WF    3014656    // bf16 [256][512]
#define WS_WI    3276800    // bf16 [256][512]
#define WS_WG    3538944    // bf16 [256][512]
#define WS_WO    3801088    // bf16 [256][512]
#define WS_FLAGS 4063232    // u32 [256] stride 64B  (arrival flags)
#define WS_REL   4079616    // u32 [8]   stride 64B  (release copies)
#define WS_END   4080128

__device__ __forceinline__ float sigm(float x) { return 1.0f / (1.0f + __expf(-x)); }

__device__ __forceinline__ unsigned short f2bf_s(float f) {
  bf16 h = __float2bfloat16(f);
  return *reinterpret_cast<unsigned short*>(&h);
}
__device__ __forceinline__ u64 pack4(float a, float b, float c, float d) {
  union { unsigned short s[4]; u64 u; } x;
  x.s[0] = f2bf_s(a); x.s[1] = f2bf_s(b); x.s[2] = f2bf_s(c); x.s[3] = f2bf_s(d);
  return x.u;
}
// sc1 relaxed atomics: BARRIER FLAGS ONLY
__device__ __forceinline__ unsigned lda4(const unsigned* p) {
  return __hip_atomic_load(p, __ATOMIC_RELAXED, __HIP_MEMORY_SCOPE_AGENT);
}
__device__ __forceinline__ void sta4(unsigned* p, unsigned v) {
  __hip_atomic_store(p, v, __ATOMIC_RELAXED, __HIP_MEMORY_SCOPE_AGENT);
}

// flag-tree grid barrier with explicit fences and busy-spin waiting.
// do_rel: this WG wrote cross-WG data this phase (emit wbl2 release fence).
// do_acq: this WG will read cross-WG data next phase (emit inv acquire fence).
__device__ __forceinline__ void gbar(unsigned* flags, unsigned* rel, int wg,
                                     unsigned val, bool do_rel, bool do_acq,
                                     volatile unsigned* go) {
  if (do_rel) __builtin_amdgcn_fence(__ATOMIC_RELEASE, "agent");  // waitcnt+wbl2
  __syncthreads();
  const int tid = threadIdx.x;
  if (wg == NWG - 1) {
    if (tid < 64) {
      if (tid == 0) sta4(&flags[(NWG - 1) * 16], val);
      for (;;) {                       // scan 256 flags, 4 per lane, no sleep
        bool ok = true;
        #pragma unroll
        for (int j = 0; j < 4; ++j)
          ok &= (lda4(&flags[(tid * 4 + j) * 16]) >= val);
        if (__ballot(ok) == ~0ull) break;
      }
      if (tid < 8) sta4(&rel[tid * 16], val);   // replicate release
      if (tid == 0) *go = val;
    }
  } else {
    if (tid == 0) {
      sta4(&flags[wg * 16], val);
      while (lda4(&rel[(wg & 7) * 16]) < val) {}   // busy poll, no sleep
      *go = val;
    }
  }
  // every thread: dummy-FMA busy spin (keeps VALU busy -> holds clocks)
  {
    float d0 = (float)tid * 1.0e-9f + 1.0f;
    while (*go < val) {
      #pragma unroll
      for (int u = 0; u < 32; ++u) d0 = __builtin_fmaf(d0, 1.000001f, 1.0e-7f);
    }
    asm volatile("" :: "v"(d0));   // keep d0 live
  }
  __syncthreads();
  if (do_acq) __builtin_amdgcn_fence(__ATOMIC_ACQUIRE, "agent");  // inv
}

// init: zero hx/flags/release, convert weights f32 -> bf16 into ws
__global__ void qlstm_init_kernel(
    const float* __restrict__ Wq, const float* __restrict__ Wk, const float* __restrict__ Wv,
    const float* __restrict__ Wf, const float* __restrict__ Wi,
    const float* __restrict__ Wg, const float* __restrict__ Wo,
    char* __restrict__ wsb) {
  const int gid = blockIdx.x * blockDim.x + threadIdx.x;
  const int stride = gridDim.x * blockDim.x;
  bf16* hx = (bf16*)(wsb + WS_HX);
  unsigned* sync = (unsigned*)(wsb + WS_FLAGS);
  for (int i = gid; i < (WS_END - WS_FLAGS) / 4; i += stride) sync[i] = 0u;
  for (int i = gid; i < 65536; i += stride) hx[i] = __float2bfloat16(0.0f);
  const float* srcs[7] = { Wq, Wk, Wv, Wf, Wi, Wg, Wo };
  const int offs[7] = { WS_WQ, WS_WK, WS_WV, WS_WF, WS_WI, WS_WG, WS_WO };
  const int lens[7] = { 262144, 262144, 262144, 131072, 131072, 131072, 131072 };
  for (int a = 0; a < 7; ++a) {
    bf16* dst = (bf16*)(wsb + offs[a]);
    const float* src = srcs[a];
    for (int i = gid; i < lens[a]; i += stride) dst[i] = __float2bfloat16(src[i]);
  }
}

__global__ void __launch_bounds__(1024, 1) qlstm_main_kernel(
    const float* __restrict__ x,
    const float* __restrict__ bfv, const float* __restrict__ biv,
    const float* __restrict__ bgv, const float* __restrict__ bov,
    float* __restrict__ out, char* __restrict__ wsb)
{
  bf16*  q_ws  = (bf16*)(wsb + WS_Q);
  bf16*  k_ws  = (bf16*)(wsb + WS_K);
  bf16*  vT_ws = (bf16*)(wsb + WS_VT);
  bf16*  hx_ws = (bf16*)(wsb + WS_HX);
  const bf16* wq_b = (const bf16*)(wsb + WS_WQ);
  const bf16* wk_b = (const bf16*)(wsb + WS_WK);
  const bf16* wv_b = (const bf16*)(wsb + WS_WV);
  const bf16* wf_b = (const bf16*)(wsb + WS_WF);
  const bf16* wi_b = (const bf16*)(wsb + WS_WI);
  const bf16* wg_b = (const bf16*)(wsb + WS_WG);
  const bf16* wo_b = (const bf16*)(wsb + WS_WO);
  unsigned* flags = (unsigned*)(wsb + WS_FLAGS);
  unsigned* rel   = (unsigned*)(wsb + WS_REL);

  const int wg   = blockIdx.x;
  const int tid  = threadIdx.x;
  const int wid  = tid >> 6;     // wave 0..15
  const int lane = tid & 63;
  const int l16  = lane & 15;
  const int kq   = lane >> 4;    // 0..3

  __shared__ unsigned short cstage[16 * 520];   // A: comb [x|hx]; D/E: attn strip
  __shared__ float          s_lds[16 * 256];    // scores f32 / h repack
  __shared__ unsigned short p_lds[16 * 264];    // softmax probs bf16 (+8 pad/row)
  __shared__ volatile unsigned go_flag;

  if (tid == 0) go_flag = 0u;
  __syncthreads();

  const int rb = wg >> 4;        // batch row-block this WG stages in phase A
  const bool strip = (wg < 16);
  f32x4 cxr = {0.f, 0.f, 0.f, 0.f};   // lane-private cell state (strip WGs)

  unsigned bexp = 0;

  for (int t = 0; t < SEQ; ++t) {
    // ============ Phase A: q,k,vT  (all WGs; 6 tiles each) ============
    {
      const int row = tid >> 6, off = (tid & 63) * 4;
      const float4 xf = *(const float4*)(x + ((size_t)t * BB + rb * 16 + row) * DD + off);
      *(u64*)(&cstage[row * 520 + off]) = pack4(xf.x, xf.y, xf.z, xf.w);
      *(u64*)(&cstage[row * 520 + 256 + off]) =
          *(const u64*)(hx_ws + (rb * 16 + row) * HH + off);
    }
    __syncthreads();
    if (wid < 6) {
      const int cb = (wg & 15) * 6 + wid;       // 0..95
      const unsigned short* crow = &cstage[l16 * 520];
      if (cb < 64) {
        // q,k: SWAPPED operands -> rows = out-col n, cols = batch
        const bf16* W = (cb < 32) ? wq_b : wk_b;
        const int n0 = (cb & 31) * 16;
        const bf16* wrow = W + (size_t)(n0 + l16) * EE;
        f32x4 acc = {0.f, 0.f, 0.f, 0.f};
        #pragma unroll
        for (int ks = 0; ks < 16; ++ks) {
          const int kg = ks * 32 + kq * 8;
          bf16x8 wf = *(const bf16x8*)(wrow + kg);
          bf16x8 cf = *(const bf16x8*)(crow + kg);
          acc = __builtin_amdgcn_mfma_f32_16x16x32_bf16(wf, cf, acc, 0, 0, 0);
        }
        bf16* dst = (cb < 32) ? q_ws : k_ws;
        *(u64*)(dst + (size_t)(rb * 16 + l16) * EE + n0 + kq * 4) =
            pack4(acc[0], acc[1], acc[2], acc[3]);
      } else {
        // v: normal order -> rows = batch, cols = e  => vT row-contig
        const int n0 = (cb - 64) * 16;
        const bf16* wrow = wv_b + (size_t)(n0 + l16) * EE;
        f32x4 acc = {0.f, 0.f, 0.f, 0.f};
        #pragma unroll
        for (int ks = 0; ks < 16; ++ks) {
          const int kg = ks * 32 + kq * 8;
          bf16x8 cf = *(const bf16x8*)(crow + kg);
          bf16x8 wf = *(const bf16x8*)(wrow + kg);
          acc = __builtin_amdgcn_mfma_f32_16x16x32_bf16(cf, wf, acc, 0, 0, 0);
        }
        *(u64*)(vT_ws + (size_t)(n0 + l16) * BB + rb * 16 + kq * 4) =
            pack4(acc[0], acc[1], acc[2], acc[3]);
      }
    }
    // all WGs wrote; only strip WGs read next
    gbar(flags, rel, wg, ++bexp, /*do_rel=*/true, /*do_acq=*/strip, &go_flag);

    // ============ Phase BCDE: strip WGs (wg<16) do scores..LSTM ============
    if (strip) {
      const int r0 = wg * 16;
      // ---- B: scores tile (strip rows x cols j0..j0+16), K=512
      {
        const int j0 = wid * 16;
        const bf16* qrow = q_ws + (size_t)(r0 + l16) * EE;
        const bf16* krow = k_ws + (size_t)(j0 + l16) * EE;
        f32x4 acc = {0.f, 0.f, 0.f, 0.f};
        #pragma unroll
        for (int ks = 0; ks < 16; ++ks) {
          const int kg = ks * 32 + kq * 8;
          bf16x8 a = *(const bf16x8*)(qrow + kg);
          bf16x8 b = *(const bf16x8*)(krow + kg);
          acc = __builtin_amdgcn_mfma_f32_16x16x32_bf16(a, b, acc, 0, 0, 0);
        }
        #pragma unroll
        for (int r = 0; r < 4; ++r)
          s_lds[(kq * 4 + r) * 256 + j0 + l16] = acc[r];
      }
      __syncthreads();
      // ---- C: softmax row i = wid
      {
        const int i = wid;
        const float4 v = *(const float4*)(&s_lds[i * 256 + lane * 4]);
        float m = fmaxf(fmaxf(v.x, v.y), fmaxf(v.z, v.w));
        #pragma unroll
        for (int off = 32; off > 0; off >>= 1) m = fmaxf(m, __shfl_xor(m, off));
        float e0 = __expf((v.x - m) * QK_SCALE);
        float e1 = __expf((v.y - m) * QK_SCALE);
        float e2 = __expf((v.z - m) * QK_SCALE);
        float e3 = __expf((v.w - m) * QK_SCALE);
        float s = e0 + e1 + e2 + e3;
        #pragma unroll
        for (int off = 32; off > 0; off >>= 1) s += __shfl_xor(s, off);
        const float rinv = 1.0f / s;
        unsigned short* pp = &p_lds[i * 264 + lane * 4];
        pp[0] = f2bf_s(e0 * rinv);
        pp[1] = f2bf_s(e1 * rinv);
        pp[2] = f2bf_s(e2 * rinv);
        pp[3] = f2bf_s(e3 * rinv);
      }
      __syncthreads();
      // ---- D: attn strip -> cstage (swapped: A=vT rows n, B=P rows i)
      #pragma unroll
      for (int q8 = 0; q8 < 2; ++q8) {
        const int n0 = wid * 16 + q8 * 256;
        const bf16* vrow = vT_ws + (size_t)(n0 + l16) * BB;
        const unsigned short* prow = &p_lds[l16 * 264];
        f32x4 acc = {0.f, 0.f, 0.f, 0.f};
        #pragma unroll
        for (int ks = 0; ks < 8; ++ks) {
          const int kg = ks * 32 + kq * 8;
          bf16x8 vf = *(const bf16x8*)(vrow + kg);
          bf16x8 pf = *(const bf16x8*)(prow + kg);
          acc = __builtin_amdgcn_mfma_f32_16x16x32_bf16(vf, pf, acc, 0, 0, 0);
        }
        *(u64*)(&cstage[l16 * 520 + n0 + kq * 4]) = pack4(acc[0], acc[1], acc[2], acc[3]);
      }
      __syncthreads();
      // ---- E: gates (wave wid owns hcol block wid*16) + LSTM update in regs
      {
        const unsigned short* arow = &cstage[l16 * 520];
        const bf16* wfr = wf_b + (size_t)(wid * 16 + l16) * EE;
        const bf16* wir = wi_b + (size_t)(wid * 16 + l16) * EE;
        const bf16* wgr = wg_b + (size_t)(wid * 16 + l16) * EE;
        const bf16* wor = wo_b + (size_t)(wid * 16 + l16) * EE;
        f32x4 aF = {0.f,0.f,0.f,0.f}, aI = {0.f,0.f,0.f,0.f};
        f32x4 aG = {0.f,0.f,0.f,0.f}, aO = {0.f,0.f,0.f,0.f};
        #pragma unroll
        for (int ks = 0; ks < 16; ++ks) {
          const int kg = ks * 32 + kq * 8;
          bf16x8 af = *(const bf16x8*)(arow + kg);
          aF = __builtin_amdgcn_mfma_f32_16x16x32_bf16(af, *(const bf16x8*)(wfr + kg), aF, 0, 0, 0);
          aI = __builtin_amdgcn_mfma_f32_16x16x32_bf16(af, *(const bf16x8*)(wir + kg), aI, 0, 0, 0);
          aG = __builtin_amdgcn_mfma_f32_16x16x32_bf16(af, *(const bf16x8*)(wgr + kg), aG, 0, 0, 0);
          aO = __builtin_amdgcn_mfma_f32_16x16x32_bf16(af, *(const bf16x8*)(wor + kg), aO, 0, 0, 0);
        }
        const int col = wid * 16 + l16;
        const float bfc = bfv[col], bic = biv[col], bgc = bgv[col], boc = bov[col];
        float h4[4], c4v[4];
        #pragma unroll
        for (int r = 0; r < 4; ++r) {
          const float F = sigm(aF[r] + bfc);
          const float I = sigm(aI[r] + bic);
          const float G = tanhf(aG[r] + bgc);
          const float O = sigm(aO[r] + boc);
          const float c2 = F * cxr[r] + I * G;
          cxr[r] = c2;
          c4v[r] = c2;
          h4[r]  = O * tanhf(c2);
        }
        #pragma unroll
        for (int r = 0; r < 4; ++r)
          s_lds[wid * 256 + (kq * 4 + r) * 16 + l16] = h4[r];
        if (t == SEQ - 1) {
          #pragma unroll
          for (int r = 0; r < 4; ++r)
            out[(size_t)SEQ * 65536 + 65536 + (size_t)(r0 + kq * 4 + r) * 256 + col] = c4v[r];
        }
      }
      __syncthreads();
      // ---- repack h: hx store (bf16) + f32 out store (row-contiguous)
      {
        const int row = tid >> 6, c4 = (tid & 63) * 4;
        float hv[4];
        #pragma unroll
        for (int e = 0; e < 4; ++e)
          hv[e] = s_lds[((c4 + e) >> 4) * 256 + row * 16 + ((c4 + e) & 15)];
        *(u64*)(hx_ws + (size_t)(r0 + row) * HH + c4) = pack4(hv[0], hv[1], hv[2], hv[3]);
        *(float4*)(out + (size_t)t * 65536 + (size_t)(r0 + row) * 256 + c4) =
            make_float4(hv[0], hv[1], hv[2], hv[3]);
        if (t == SEQ - 1)
          *(float4*)(out + (size_t)SEQ * 65536 + (size_t)(r0 + row) * 256 + c4) =
              make_float4(hv[0], hv[1], hv[2], hv[3]);
      }
    }
    // only strip WGs wrote (hx); all WGs read hx in next A
    gbar(flags, rel, wg, ++bexp, /*do_rel=*/strip, /*do_acq=*/true, &go_flag);
  }
}

extern "C" void kernel_launch(void* const* d_in, const int* in_sizes, int n_in,
                              void* d_out, int out_size, void* d_ws, size_t ws_size,
                              hipStream_t stream) {
  const float* x   = (const float*)d_in[0];
  const float* Wq  = (const float*)d_in[1];
  const float* Wk  = (const float*)d_in[2];
  const float* Wv  = (const float*)d_in[3];
  const float* Wf  = (const float*)d_in[4];
  const float* bfv = (const float*)d_in[5];
  const float* Wi  = (const float*)d_in[6];
  const float* biv = (const float*)d_in[7];
  const float* Wgg = (const float*)d_in[8];
  const float* bgv = (const float*)d_in[9];
  const float* Wo  = (const float*)d_in[10];
  const float* bov = (const float*)d_in[11];
  float* out = (float*)d_out;
  char* wsb = (char*)d_ws;

  hipLaunchKernelGGL(qlstm_init_kernel, dim3(512), dim3(256), 0, stream,
                     Wq, Wk, Wv, Wf, Wi, Wgg, Wo, wsb);

  void* args[] = { (void*)&x, (void*)&bfv, (void*)&biv, (void*)&bgv, (void*)&bov,
                   (void*)&out, (void*)&wsb };
  hipLaunchCooperativeKernel((void*)qlstm_main_kernel, dim3(NWG), dim3(1024),
                             args, 0, stream);
}

// Round 9
// 47653.278 us; speedup vs baseline: 1.6781x; 1.6781x over previous
//
#include <hip/hip_runtime.h>
#include <hip/hip_bf16.h>

// QLSTM (S=512,B=256,D=256,H=256,E=512), f32 in/out, bf16 MFMA internals.
// Per-XCD-replicated design: 256 WGs x 1024 threads, 1 WG/CU (big LDS),
// grouped by runtime XCC_ID into 8 groups of exactly 32 WGs.
//   A    : every XCD computes the FULL k,vT into its own per-XCD buffer
//          (plain stores -> own L2); strip WGs compute their q into LDS.
//   BCDE : 2 strip WGs per XCD read k/vT from their XCD's L2 via sc0
//          16B loads (batched, 8-deep, single vmcnt). All-LDS afterwards.
// Cross-XCD data = hx only (128KB/step, sc1). Barrier1 = XCD-local flag
// scan; Barrier2 = global flag-tree. No cache-maintenance fences anywhere.

typedef __hip_bfloat16 bf16;
typedef __attribute__((ext_vector_type(8))) short bf16x8;   // 8 bf16 = 4 VGPR
typedef __attribute__((ext_vector_type(4))) float f32x4;
typedef unsigned long long u64;

#define SEQ 512
#define BB  256
#define DD  256
#define HH  256
#define EE  512
#define NWG 256
#define QK_SCALE 0.04419417382415922f  // 1/sqrt(512)

// ws layout (bytes)
#define WS_KX    0          // bf16 [8][256][512]  per-XCD k
#define WS_VTX   2097152    // bf16 [8][512][256]  per-XCD vT
#define WS_HX    4194304    // bf16 [256][256]     (sc1 domain)
#define WS_RANKC 4325376    // u32 [8]  stride 64B rank tickets
#define WS_XFL   4325888    // u32 [256] stride 64B  XCD-local arrival flags
#define WS_GFL   4342272    // u32 [256] stride 64B  global arrival flags
#define WS_GREL  4358656    // u32 [8]   stride 64B  global release copies
#define WS_WQ    4359168    // bf16 [512][512]
#define WS_WK    4883456    // bf16 [512][512]
#define WS_WV    5407744    // bf16 [512][512]
#define WS_WF    5932032    // bf16 [256][512]
#define WS_WI    6194176    // bf16 [256][512]
#define WS_WG    6456320    // bf16 [256][512]
#define WS_WO    6718464    // bf16 [256][512]
#define WS_END   6980608

__device__ __forceinline__ float sigm(float x) { return 1.0f / (1.0f + __expf(-x)); }

__device__ __forceinline__ unsigned short f2bf_s(float f) {
  bf16 h = __float2bfloat16(f);
  return *reinterpret_cast<unsigned short*>(&h);
}
__device__ __forceinline__ u64 pack4(float a, float b, float c, float d) {
  union { unsigned short s[4]; u64 u; } x;
  x.s[0] = f2bf_s(a); x.s[1] = f2bf_s(b); x.s[2] = f2bf_s(c); x.s[3] = f2bf_s(d);
  return x.u;
}
// sc1 relaxed atomics (LLC): hx + sync flags only
__device__ __forceinline__ u64 lda8(const void* p) {
  return __hip_atomic_load((const u64*)p, __ATOMIC_RELAXED, __HIP_MEMORY_SCOPE_AGENT);
}
__device__ __forceinline__ void sta8(void* p, u64 v) {
  __hip_atomic_store((u64*)p, v, __ATOMIC_RELAXED, __HIP_MEMORY_SCOPE_AGENT);
}
__device__ __forceinline__ unsigned lda4(const unsigned* p) {
  return __hip_atomic_load(p, __ATOMIC_RELAXED, __HIP_MEMORY_SCOPE_AGENT);
}
__device__ __forceinline__ void sta4(unsigned* p, unsigned v) {
  __hip_atomic_store(p, v, __ATOMIC_RELAXED, __HIP_MEMORY_SCOPE_AGENT);
}

// init: zero hx + sync region, convert weights f32 -> bf16
__global__ void qlstm_init_kernel(
    const float* __restrict__ Wq, const float* __restrict__ Wk, const float* __restrict__ Wv,
    const float* __restrict__ Wf, const float* __restrict__ Wi,
    const float* __restrict__ Wg, const float* __restrict__ Wo,
    char* __restrict__ wsb) {
  const int gid = blockIdx.x * blockDim.x + threadIdx.x;
  const int stride = gridDim.x * blockDim.x;
  bf16* hx = (bf16*)(wsb + WS_HX);
  unsigned* sync = (unsigned*)(wsb + WS_RANKC);
  for (int i = gid; i < (WS_WQ - WS_RANKC) / 4; i += stride) sync[i] = 0u;
  for (int i = gid; i < 65536; i += stride) hx[i] = __float2bfloat16(0.0f);
  const float* srcs[7] = { Wq, Wk, Wv, Wf, Wi, Wg, Wo };
  const int offs[7] = { WS_WQ, WS_WK, WS_WV, WS_WF, WS_WI, WS_WG, WS_WO };
  const int lens[7] = { 262144, 262144, 262144, 131072, 131072, 131072, 131072 };
  for (int a = 0; a < 7; ++a) {
    bf16* dst = (bf16*)(wsb + offs[a]);
    const float* src = srcs[a];
    for (int i = gid; i < lens[a]; i += stride) dst[i] = __float2bfloat16(src[i]);
  }
}

__global__ void __launch_bounds__(1024, 1) qlstm_main_kernel(
    const float* __restrict__ x,
    const float* __restrict__ bfv, const float* __restrict__ biv,
    const float* __restrict__ bgv, const float* __restrict__ bov,
    float* __restrict__ out, char* __restrict__ wsb)
{
  bf16*  hx_ws = (bf16*)(wsb + WS_HX);
  const bf16* wq_b = (const bf16*)(wsb + WS_WQ);
  const bf16* wk_b = (const bf16*)(wsb + WS_WK);
  const bf16* wv_b = (const bf16*)(wsb + WS_WV);
  const bf16* wf_b = (const bf16*)(wsb + WS_WF);
  const bf16* wi_b = (const bf16*)(wsb + WS_WI);
  const bf16* wg_b = (const bf16*)(wsb + WS_WG);
  const bf16* wo_b = (const bf16*)(wsb + WS_WO);
  unsigned* rankc  = (unsigned*)(wsb + WS_RANKC);
  unsigned* xfl    = (unsigned*)(wsb + WS_XFL);
  unsigned* gfl    = (unsigned*)(wsb + WS_GFL);
  unsigned* grel   = (unsigned*)(wsb + WS_GREL);

  const int tid  = threadIdx.x;
  const int wid  = tid >> 6;     // wave 0..15
  const int lane = tid & 63;
  const int l16  = lane & 15;
  const int kq   = lane >> 4;    // 0..3

  __shared__ unsigned short cstage[16 * 520];   // A: comb [x|hx]; D/E: attn
  __shared__ unsigned short q_lds[16 * 520];    // strip q, batch-major
  __shared__ float          s_lds[16 * 256];    // scores f32 / h repack
  __shared__ unsigned short p_lds[16 * 264];    // probs bf16 (+8 pad/row)
  __shared__ char           pad_lds[32768];     // force 1 WG/CU (LDS > 80KB)
  __shared__ unsigned s_xcd, s_rank;

  if (tid == 1023) pad_lds[0] = 1;   // keep pad_lds allocated
  if (tid == 0) {
    unsigned xv;
    asm volatile("s_getreg_b32 %0, hwreg(HW_REG_XCC_ID, 0, 32)" : "=s"(xv));
    xv &= 7u;
    s_xcd = xv;
    s_rank = __hip_atomic_fetch_add(&rankc[xv * 16], 1u,
                                    __ATOMIC_RELAXED, __HIP_MEMORY_SCOPE_AGENT);
  }
  __syncthreads();
  const int xcd  = (int)s_xcd;
  const int rank = (int)s_rank;
  const int gid  = xcd * 32 + rank;         // unique 0..255
  const int rb   = rank >> 1;               // row-block this WG stages
  const bool is_strip   = (rank == 4 * xcd) || (rank == 4 * xcd + 2);
  const bool is_partner = (rank == 4 * xcd + 1) || (rank == 4 * xcd + 3);
  const bool is_agg     = (gid == 31);      // xcd 0, rank 31 (never strip)
  const int  strip_s    = rb;               // for strip WGs: rb == global strip

  bf16* kx  = (bf16*)(wsb + WS_KX)  + (size_t)xcd * 131072;  // [256][512]
  bf16* vtx = (bf16*)(wsb + WS_VTX) + (size_t)xcd * 131072;  // [512][256]

  f32x4 cxr = {0.f, 0.f, 0.f, 0.f};   // strip lane-private cell state

  for (int t = 0; t < SEQ; ++t) {
    const unsigned val = (unsigned)(t + 1);
    // ============ Phase A ============
    {  // stage comb = [x_t | hx] rows rb*16.. into cstage
      const int row = tid >> 6, off = (tid & 63) * 4;
      const float4 xf = *(const float4*)(x + ((size_t)t * BB + rb * 16 + row) * DD + off);
      *(u64*)(&cstage[row * 520 + off]) = pack4(xf.x, xf.y, xf.z, xf.w);
      *(u64*)(&cstage[row * 520 + 256 + off]) = lda8(hx_ws + (rb * 16 + row) * HH + off);
    }
    __syncthreads();
    {
      const unsigned short* crow = &cstage[l16 * 520];
      if (is_strip) {
        // q for own strip -> q_lds (swapped: A=Wq rows n, B=comb)
        #pragma unroll
        for (int h = 0; h < 2; ++h) {
          const int cb = wid + h * 16;
          const bf16* wrow = wq_b + (size_t)(cb * 16 + l16) * EE;
          f32x4 acc = {0.f, 0.f, 0.f, 0.f};
          #pragma unroll
          for (int ks = 0; ks < 16; ++ks) {
            const int kg = ks * 32 + kq * 8;
            bf16x8 wf = *(const bf16x8*)(wrow + kg);
            bf16x8 cf = *(const bf16x8*)(crow + kg);
            acc = __builtin_amdgcn_mfma_f32_16x16x32_bf16(wf, cf, acc, 0, 0, 0);
          }
          *(u64*)(&q_lds[l16 * 520 + cb * 16 + kq * 4]) =
              pack4(acc[0], acc[1], acc[2], acc[3]);
        }
      } else {
        const bool do_k  = is_partner || ((rank & 1) == 0);
        const bool do_vt = is_partner || ((rank & 1) == 1);
        if (do_k) {
          #pragma unroll
          for (int h = 0; h < 2; ++h) {
            const int cb = wid + h * 16;
            const bf16* wrow = wk_b + (size_t)(cb * 16 + l16) * EE;
            f32x4 acc = {0.f, 0.f, 0.f, 0.f};
            #pragma unroll
            for (int ks = 0; ks < 16; ++ks) {
              const int kg = ks * 32 + kq * 8;
              bf16x8 wf = *(const bf16x8*)(wrow + kg);
              bf16x8 cf = *(const bf16x8*)(crow + kg);
              acc = __builtin_amdgcn_mfma_f32_16x16x32_bf16(wf, cf, acc, 0, 0, 0);
            }
            *(u64*)(kx + (size_t)(rb * 16 + l16) * EE + cb * 16 + kq * 4) =
                pack4(acc[0], acc[1], acc[2], acc[3]);
          }
        }
        if (do_vt) {
          #pragma unroll
          for (int h = 0; h < 2; ++h) {
            const int cb = wid + h * 16;
            const bf16* wrow = wv_b + (size_t)(cb * 16 + l16) * EE;
            f32x4 acc = {0.f, 0.f, 0.f, 0.f};
            #pragma unroll
            for (int ks = 0; ks < 16; ++ks) {
              const int kg = ks * 32 + kq * 8;
              bf16x8 cf = *(const bf16x8*)(crow + kg);
              bf16x8 wf = *(const bf16x8*)(wrow + kg);
              acc = __builtin_amdgcn_mfma_f32_16x16x32_bf16(cf, wf, acc, 0, 0, 0);
            }
            *(u64*)(vtx + (size_t)(cb * 16 + l16) * BB + rb * 16 + kq * 4) =
                pack4(acc[0], acc[1], acc[2], acc[3]);
          }
        }
      }
    }
    // ---- barrier 1: XCD-local arrival; only strips wait ----
    asm volatile("s_waitcnt vmcnt(0)" ::: "memory");  // k/vT in L2 before flag
    __syncthreads();
    if (tid == 0) sta4(&xfl[gid * 16], val);

    if (is_strip) {
      if (tid < 32) {
        while (lda4(&xfl[(xcd * 32 + tid) * 16]) < val)
          __builtin_amdgcn_s_sleep(1);
      }
      __syncthreads();
      asm volatile("" ::: "memory");

      const int r0 = strip_s * 16;
      // ---- B: scores (wave wid -> cols wid*16..), K=512, k via sc0 ----
      {
        const int j0 = wid * 16;
        const unsigned short* qrow = &q_lds[l16 * 520];
        const bf16* krow = kx + (size_t)(j0 + l16) * EE;
        f32x4 acc = {0.f, 0.f, 0.f, 0.f};
        #pragma unroll
        for (int half = 0; half < 2; ++half) {
          bf16x8 kf[8];
          #pragma unroll
          for (int u = 0; u < 8; ++u)
            asm volatile("global_load_dwordx4 %0, %1, off sc0"
                         : "=v"(kf[u])
                         : "v"(krow + (half * 8 + u) * 32 + kq * 8));
          asm volatile("s_waitcnt vmcnt(0)" ::: "memory");
          __builtin_amdgcn_sched_barrier(0);
          #pragma unroll
          for (int u = 0; u < 8; ++u) {
            bf16x8 qf = *(const bf16x8*)(qrow + (half * 8 + u) * 32 + kq * 8);
            acc = __builtin_amdgcn_mfma_f32_16x16x32_bf16(qf, kf[u], acc, 0, 0, 0);
          }
        }
        #pragma unroll
        for (int r = 0; r < 4; ++r)
          s_lds[(kq * 4 + r) * 256 + j0 + l16] = acc[r];
      }
      __syncthreads();
      // ---- C: softmax row i = wid ----
      {
        const int i = wid;
        const float4 v = *(const float4*)(&s_lds[i * 256 + lane * 4]);
        float m = fmaxf(fmaxf(v.x, v.y), fmaxf(v.z, v.w));
        #pragma unroll
        for (int off = 32; off > 0; off >>= 1) m = fmaxf(m, __shfl_xor(m, off));
        float e0 = __expf((v.x - m) * QK_SCALE);
        float e1 = __expf((v.y - m) * QK_SCALE);
        float e2 = __expf((v.z - m) * QK_SCALE);
        float e3 = __expf((v.w - m) * QK_SCALE);
        float s = e0 + e1 + e2 + e3;
        #pragma unroll
        for (int off = 32; off > 0; off >>= 1) s += __shfl_xor(s, off);
        const float rinv = 1.0f / s;
        unsigned short* pp = &p_lds[i * 264 + lane * 4];
        pp[0] = f2bf_s(e0 * rinv);
        pp[1] = f2bf_s(e1 * rinv);
        pp[2] = f2bf_s(e2 * rinv);
        pp[3] = f2bf_s(e3 * rinv);
      }
      __syncthreads();
      // ---- D: attn -> cstage (A=vT rows n via sc0, B=P rows) K=256 ----
      #pragma unroll
      for (int q8 = 0; q8 < 2; ++q8) {
        const int n0 = wid * 16 + q8 * 256;
        const bf16* vrow = vtx + (size_t)(n0 + l16) * BB;
        const unsigned short* prow = &p_lds[l16 * 264];
        f32x4 acc = {0.f, 0.f, 0.f, 0.f};
        bf16x8 vf[8];
        #pragma unroll
        for (int u = 0; u < 8; ++u)
          asm volatile("global_load_dwordx4 %0, %1, off sc0"
                       : "=v"(vf[u]) : "v"(vrow + u * 32 + kq * 8));
        asm volatile("s_waitcnt vmcnt(0)" ::: "memory");
        __builtin_amdgcn_sched_barrier(0);
        #pragma unroll
        for (int u = 0; u < 8; ++u) {
          bf16x8 pf = *(const bf16x8*)(prow + u * 32 + kq * 8);
          acc = __builtin_amdgcn_mfma_f32_16x16x32_bf16(vf[u], pf, acc, 0, 0, 0);
        }
        *(u64*)(&cstage[l16 * 520 + n0 + kq * 4]) = pack4(acc[0], acc[1], acc[2], acc[3]);
      }
      __syncthreads();
      // ---- E: gates (wave wid -> hcols wid*16..) + LSTM in regs ----
      {
        const unsigned short* arow = &cstage[l16 * 520];
        const bf16* wfr = wf_b + (size_t)(wid * 16 + l16) * EE;
        const bf16* wir = wi_b + (size_t)(wid * 16 + l16) * EE;
        const bf16* wgr = wg_b + (size_t)(wid * 16 + l16) * EE;
        const bf16* wor = wo_b + (size_t)(wid * 16 + l16) * EE;
        f32x4 aF = {0.f,0.f,0.f,0.f}, aI = {0.f,0.f,0.f,0.f};
        f32x4 aG = {0.f,0.f,0.f,0.f}, aO = {0.f,0.f,0.f,0.f};
        #pragma unroll
        for (int ks = 0; ks < 16; ++ks) {
          const int kg = ks * 32 + kq * 8;
          bf16x8 af = *(const bf16x8*)(arow + kg);
          aF = __builtin_amdgcn_mfma_f32_16x16x32_bf16(af, *(const bf16x8*)(wfr + kg), aF, 0, 0, 0);
          aI = __builtin_amdgcn_mfma_f32_16x16x32_bf16(af, *(const bf16x8*)(wir + kg), aI, 0, 0, 0);
          aG = __builtin_amdgcn_mfma_f32_16x16x32_bf16(af, *(const bf16x8*)(wgr + kg), aG, 0, 0, 0);
          aO = __builtin_amdgcn_mfma_f32_16x16x32_bf16(af, *(const bf16x8*)(wor + kg), aO, 0, 0, 0);
        }
        const int col = wid * 16 + l16;
        const float bfc = bfv[col], bic = biv[col], bgc = bgv[col], boc = bov[col];
        float h4[4], c4v[4];
        #pragma unroll
        for (int r = 0; r < 4; ++r) {
          const float F = sigm(aF[r] + bfc);
          const float I = sigm(aI[r] + bic);
          const float G = tanhf(aG[r] + bgc);
          const float O = sigm(aO[r] + boc);
          const float c2 = F * cxr[r] + I * G;
          cxr[r] = c2;
          c4v[r] = c2;
          h4[r]  = O * tanhf(c2);
        }
        #pragma unroll
        for (int r = 0; r < 4; ++r)
          s_lds[wid * 256 + (kq * 4 + r) * 16 + l16] = h4[r];
        if (t == SEQ - 1) {
          #pragma unroll
          for (int r = 0; r < 4; ++r)
            out[(size_t)SEQ * 65536 + 65536 + (size_t)(r0 + kq * 4 + r) * 256 + col] = c4v[r];
        }
      }
      __syncthreads();
      // ---- repack h: hx (sc1) + out (f32 cached) ----
      {
        const int row = tid >> 6, c4 = (tid & 63) * 4;
        float hv[4];
        #pragma unroll
        for (int e = 0; e < 4; ++e)
          hv[e] = s_lds[((c4 + e) >> 4) * 256 + row * 16 + ((c4 + e) & 15)];
        sta8(hx_ws + (size_t)(r0 + row) * HH + c4, pack4(hv[0], hv[1], hv[2], hv[3]));
        *(float4*)(out + (size_t)t * 65536 + (size_t)(r0 + row) * 256 + c4) =
            make_float4(hv[0], hv[1], hv[2], hv[3]);
        if (t == SEQ - 1)
          *(float4*)(out + (size_t)SEQ * 65536 + (size_t)(r0 + row) * 256 + c4) =
              make_float4(hv[0], hv[1], hv[2], hv[3]);
      }
    }
    // ---- barrier 2: global flag-tree ----
    asm volatile("s_waitcnt vmcnt(0)" ::: "memory");  // hx at LLC before flag
    __syncthreads();
    if (is_agg) {
      if (tid < 64) {
        if (tid == 0) sta4(&gfl[gid * 16], val);
        for (;;) {
          bool ok = true;
          #pragma unroll
          for (int j = 0; j < 4; ++j)
            ok &= (lda4(&gfl[(tid * 4 + j) * 16]) >= val);
          if (__ballot(ok) == ~0ull) break;
          __builtin_amdgcn_s_sleep(2);
        }
        if (tid < 8) sta4(&grel[tid * 16], val);
      }
    } else if (tid == 0) {
      sta4(&gfl[gid * 16], val);
      while (lda4(&grel[(gid & 7) * 16]) < val)
        __builtin_amdgcn_s_sleep(2);
    }
    __syncthreads();
    asm volatile("" ::: "memory");
  }
}

extern "C" void kernel_launch(void* const* d_in, const int* in_sizes, int n_in,
                              void* d_out, int out_size, void* d_ws, size_t ws_size,
                              hipStream_t stream) {
  const float* x   = (const float*)d_in[0];
  const float* Wq  = (const float*)d_in[1];
  const float* Wk  = (const float*)d_in[2];
  const float* Wv  = (const float*)d_in[3];
  const float* Wf  = (const float*)d_in[4];
  const float* bfv = (const float*)d_in[5];
  const float* Wi  = (const float*)d_in[6];
  const float* biv = (const float*)d_in[7];
  const float* Wgg = (const float*)d_in[8];
  const float* bgv = (const float*)d_in[9];
  const float* Wo  = (const float*)d_in[10];
  const float* bov = (const float*)d_in[11];
  float* out = (float*)d_out;
  char* wsb = (char*)d_ws;

  hipLaunchKernelGGL(qlstm_init_kernel, dim3(512), dim3(256), 0, stream,
                     Wq, Wk, Wv, Wf, Wi, Wgg, Wo, wsb);

  void* args[] = { (void*)&x, (void*)&bfv, (void*)&biv, (void*)&bgv, (void*)&bov,
                   (void*)&out, (void*)&wsb };
  hipLaunchCooperativeKernel((void*)qlstm_main_kernel, dim3(NWG), dim3(1024),
                             args, 0, stream);
}

// Round 10
// 36682.391 us; speedup vs baseline: 2.1799x; 1.2991x over previous
//
#include <hip/hip_runtime.h>
#include <hip/hip_bf16.h>

// QLSTM (S=512,B=256,D=256,H=256,E=512), f32 in/out, bf16 MFMA internals.
// MULTI-LAUNCH design: 2 small kernels per time-step, 512 steps, all
// captured in one graph. Launch boundaries provide grid-wide sync and
// cache coherence -> ALL memory ops are plain cached loads/stores.
//   qkv_kernel  (384 WG x 256): q,k,vT = [x_t|hx] @ [Wq|Wk|Wv]^T
//   bcde_kernel (16 WG x 1024): scores->softmax->attn->gates->LSTM per strip

typedef __hip_bfloat16 bf16;
typedef __attribute__((ext_vector_type(8))) short bf16x8;   // 8 bf16 = 4 VGPR
typedef __attribute__((ext_vector_type(4))) float f32x4;
typedef unsigned long long u64;

#define SEQ 512
#define BB  256
#define DD  256
#define HH  256
#define EE  512
#define QK_SCALE 0.04419417382415922f  // 1/sqrt(512)

// ws layout (bytes)
#define WS_Q    0          // bf16 [256][512]  batch-major
#define WS_K    262144     // bf16 [256][512]  batch-major
#define WS_VT   524288     // bf16 [512][256]  e-major (v transposed)
#define WS_HX   786432     // bf16 [256][256]  batch-major
#define WS_CX   917504     // f32  lane-private layout [16][16][64][4]
#define WS_WQ   1179648    // bf16 [512][512]
#define WS_WK   1703936    // bf16 [512][512]
#define WS_WV   2228224    // bf16 [512][512]
#define WS_WF   2752512    // bf16 [256][512]
#define WS_WI   3014656    // bf16 [256][512]
#define WS_WG   3276800    // bf16 [256][512]
#define WS_WO   3538944    // bf16 [256][512]
#define WS_END  3801088

__device__ __forceinline__ float sigm(float x) { return 1.0f / (1.0f + __expf(-x)); }

__device__ __forceinline__ unsigned short f2bf_s(float f) {
  bf16 h = __float2bfloat16(f);
  return *reinterpret_cast<unsigned short*>(&h);
}
__device__ __forceinline__ u64 pack4(float a, float b, float c, float d) {
  union { unsigned short s[4]; u64 u; } x;
  x.s[0] = f2bf_s(a); x.s[1] = f2bf_s(b); x.s[2] = f2bf_s(c); x.s[3] = f2bf_s(d);
  return x.u;
}
__device__ __forceinline__ bf16x8 cvt8(float4 a, float4 b) {
  bf16x8 r;
  r[0] = (short)f2bf_s(a.x); r[1] = (short)f2bf_s(a.y);
  r[2] = (short)f2bf_s(a.z); r[3] = (short)f2bf_s(a.w);
  r[4] = (short)f2bf_s(b.x); r[5] = (short)f2bf_s(b.y);
  r[6] = (short)f2bf_s(b.z); r[7] = (short)f2bf_s(b.w);
  return r;
}

// ---------------- init: zero hx/cx, convert weights f32 -> bf16 ------------
__global__ void qlstm_init_kernel(
    const float* __restrict__ Wq, const float* __restrict__ Wk, const float* __restrict__ Wv,
    const float* __restrict__ Wf, const float* __restrict__ Wi,
    const float* __restrict__ Wg, const float* __restrict__ Wo,
    char* __restrict__ wsb) {
  const int gid = blockIdx.x * blockDim.x + threadIdx.x;
  const int stride = gridDim.x * blockDim.x;
  bf16*  hx = (bf16*)(wsb + WS_HX);
  float* cx = (float*)(wsb + WS_CX);
  for (int i = gid; i < 65536; i += stride) { hx[i] = __float2bfloat16(0.0f); cx[i] = 0.0f; }
  const float* srcs[7] = { Wq, Wk, Wv, Wf, Wi, Wg, Wo };
  const int offs[7] = { WS_WQ, WS_WK, WS_WV, WS_WF, WS_WI, WS_WG, WS_WO };
  const int lens[7] = { 262144, 262144, 262144, 131072, 131072, 131072, 131072 };
  for (int a = 0; a < 7; ++a) {
    bf16* dst = (bf16*)(wsb + offs[a]);
    const float* src = srcs[a];
    for (int i = gid; i < lens[a]; i += stride) dst[i] = __float2bfloat16(src[i]);
  }
}

// ---------------- A: q,k,vT (384 WGs x 256 thr; 1 tile per wave) -----------
__global__ void __launch_bounds__(256) qkv_kernel(
    const float* __restrict__ x, char* __restrict__ wsb, int t)
{
  bf16* q_ws  = (bf16*)(wsb + WS_Q);
  bf16* k_ws  = (bf16*)(wsb + WS_K);
  bf16* vT_ws = (bf16*)(wsb + WS_VT);
  const bf16* hx_ws = (const bf16*)(wsb + WS_HX);
  const bf16* wq_b = (const bf16*)(wsb + WS_WQ);
  const bf16* wk_b = (const bf16*)(wsb + WS_WK);
  const bf16* wv_b = (const bf16*)(wsb + WS_WV);

  const int tid  = threadIdx.x;
  const int wid  = tid >> 6;
  const int lane = tid & 63;
  const int l16  = lane & 15;
  const int kq   = lane >> 4;

  const int gw   = blockIdx.x * 4 + wid;   // 0..1535
  const int type = gw >> 9;                // 0=q, 1=k, 2=v
  const int idx  = gw & 511;
  const int rb   = idx >> 5;               // batch row-block 0..15
  const int n0   = (idx & 31) * 16;        // output col block

  const float* xrow = x + ((size_t)t * BB + rb * 16 + l16) * DD;
  const bf16*  hrow = hx_ws + (rb * 16 + l16) * HH;

  if (type < 2) {
    // q,k SWAPPED: A = W rows n, B = comb rows batch
    const bf16* W = (type == 0) ? wq_b : wk_b;
    const bf16* wrow = W + (size_t)(n0 + l16) * EE;
    f32x4 acc = {0.f, 0.f, 0.f, 0.f};
    #pragma unroll
    for (int ks = 0; ks < 16; ++ks) {
      const int kg = ks * 32 + kq * 8;
      bf16x8 cf;
      if (ks < 8) {
        const float4* xf = (const float4*)(xrow + kg);
        cf = cvt8(xf[0], xf[1]);
      } else {
        cf = *(const bf16x8*)(hrow + (kg - 256));
      }
      bf16x8 wf = *(const bf16x8*)(wrow + kg);
      acc = __builtin_amdgcn_mfma_f32_16x16x32_bf16(wf, cf, acc, 0, 0, 0);
    }
    bf16* dst = (type == 0) ? q_ws : k_ws;
    *(u64*)(dst + (size_t)(rb * 16 + l16) * EE + n0 + kq * 4) =
        pack4(acc[0], acc[1], acc[2], acc[3]);
  } else {
    // v normal: A = comb rows batch, B = Wv rows n  => vT row-contig
    const bf16* wrow = wv_b + (size_t)(n0 + l16) * EE;
    f32x4 acc = {0.f, 0.f, 0.f, 0.f};
    #pragma unroll
    for (int ks = 0; ks < 16; ++ks) {
      const int kg = ks * 32 + kq * 8;
      bf16x8 cf;
      if (ks < 8) {
        const float4* xf = (const float4*)(xrow + kg);
        cf = cvt8(xf[0], xf[1]);
      } else {
        cf = *(const bf16x8*)(hrow + (kg - 256));
      }
      bf16x8 wf = *(const bf16x8*)(wrow + kg);
      acc = __builtin_amdgcn_mfma_f32_16x16x32_bf16(cf, wf, acc, 0, 0, 0);
    }
    *(u64*)(vT_ws + (size_t)(n0 + l16) * BB + rb * 16 + kq * 4) =
        pack4(acc[0], acc[1], acc[2], acc[3]);
  }
}

// ---------------- BCDE: per-strip scores..LSTM (16 WGs x 1024) -------------
__global__ void __launch_bounds__(1024) bcde_kernel(
    const float* __restrict__ bfv, const float* __restrict__ biv,
    const float* __restrict__ bgv, const float* __restrict__ bov,
    float* __restrict__ out, char* __restrict__ wsb, int t)
{
  const bf16* q_ws  = (const bf16*)(wsb + WS_Q);
  const bf16* k_ws  = (const bf16*)(wsb + WS_K);
  const bf16* vT_ws = (const bf16*)(wsb + WS_VT);
  bf16*  hx_ws = (bf16*)(wsb + WS_HX);
  float* cx_ws = (float*)(wsb + WS_CX);
  const bf16* wf_b = (const bf16*)(wsb + WS_WF);
  const bf16* wi_b = (const bf16*)(wsb + WS_WI);
  const bf16* wg_b = (const bf16*)(wsb + WS_WG);
  const bf16* wo_b = (const bf16*)(wsb + WS_WO);

  const int wg   = blockIdx.x;     // strip 0..15
  const int tid  = threadIdx.x;
  const int wid  = tid >> 6;       // wave 0..15
  const int lane = tid & 63;
  const int l16  = lane & 15;
  const int kq   = lane >> 4;
  const int r0   = wg * 16;

  __shared__ unsigned short cstage[16 * 520];   // attn strip bf16
  __shared__ float          s_lds[16 * 256];    // scores f32 / h repack
  __shared__ unsigned short p_lds[16 * 264];    // probs bf16 (+8 pad/row)

  // ---- B: scores tile (strip rows x cols j0..j0+16), K=512
  {
    const int j0 = wid * 16;
    const bf16* qrow = q_ws + (size_t)(r0 + l16) * EE;
    const bf16* krow = k_ws + (size_t)(j0 + l16) * EE;
    f32x4 acc = {0.f, 0.f, 0.f, 0.f};
    #pragma unroll
    for (int ks = 0; ks < 16; ++ks) {
      const int kg = ks * 32 + kq * 8;
      bf16x8 a = *(const bf16x8*)(qrow + kg);
      bf16x8 b = *(const bf16x8*)(krow + kg);
      acc = __builtin_amdgcn_mfma_f32_16x16x32_bf16(a, b, acc, 0, 0, 0);
    }
    #pragma unroll
    for (int r = 0; r < 4; ++r)
      s_lds[(kq * 4 + r) * 256 + j0 + l16] = acc[r];
  }
  __syncthreads();
  // ---- C: softmax row i = wid
  {
    const int i = wid;
    const float4 v = *(const float4*)(&s_lds[i * 256 + lane * 4]);
    float m = fmaxf(fmaxf(v.x, v.y), fmaxf(v.z, v.w));
    #pragma unroll
    for (int off = 32; off > 0; off >>= 1) m = fmaxf(m, __shfl_xor(m, off));
    float e0 = __expf((v.x - m) * QK_SCALE);
    float e1 = __expf((v.y - m) * QK_SCALE);
    float e2 = __expf((v.z - m) * QK_SCALE);
    float e3 = __expf((v.w - m) * QK_SCALE);
    float s = e0 + e1 + e2 + e3;
    #pragma unroll
    for (int off = 32; off > 0; off >>= 1) s += __shfl_xor(s, off);
    const float rinv = 1.0f / s;
    unsigned short* pp = &p_lds[i * 264 + lane * 4];
    pp[0] = f2bf_s(e0 * rinv);
    pp[1] = f2bf_s(e1 * rinv);
    pp[2] = f2bf_s(e2 * rinv);
    pp[3] = f2bf_s(e3 * rinv);
  }
  __syncthreads();
  // ---- D: attn strip -> cstage (swapped: A=vT rows n, B=P rows i), K=256
  #pragma unroll
  for (int q8 = 0; q8 < 2; ++q8) {
    const int n0 = wid * 16 + q8 * 256;
    const bf16* vrow = vT_ws + (size_t)(n0 + l16) * BB;
    const unsigned short* prow = &p_lds[l16 * 264];
    f32x4 acc = {0.f, 0.f, 0.f, 0.f};
    #pragma unroll
    for (int ks = 0; ks < 8; ++ks) {
      const int kg = ks * 32 + kq * 8;
      bf16x8 vf = *(const bf16x8*)(vrow + kg);
      bf16x8 pf = *(const bf16x8*)(prow + kg);
      acc = __builtin_amdgcn_mfma_f32_16x16x32_bf16(vf, pf, acc, 0, 0, 0);
    }
    *(u64*)(&cstage[l16 * 520 + n0 + kq * 4]) = pack4(acc[0], acc[1], acc[2], acc[3]);
  }
  __syncthreads();
  // ---- E: gates (wave wid owns hcol block wid*16) + LSTM update
  {
    const unsigned short* arow = &cstage[l16 * 520];
    const bf16* wfr = wf_b + (size_t)(wid * 16 + l16) * EE;
    const bf16* wir = wi_b + (size_t)(wid * 16 + l16) * EE;
    const bf16* wgr = wg_b + (size_t)(wid * 16 + l16) * EE;
    const bf16* wor = wo_b + (size_t)(wid * 16 + l16) * EE;
    f32x4 aF = {0.f,0.f,0.f,0.f}, aI = {0.f,0.f,0.f,0.f};
    f32x4 aG = {0.f,0.f,0.f,0.f}, aO = {0.f,0.f,0.f,0.f};
    #pragma unroll
    for (int ks = 0; ks < 16; ++ks) {
      const int kg = ks * 32 + kq * 8;
      bf16x8 af = *(const bf16x8*)(arow + kg);
      aF = __builtin_amdgcn_mfma_f32_16x16x32_bf16(af, *(const bf16x8*)(wfr + kg), aF, 0, 0, 0);
      aI = __builtin_amdgcn_mfma_f32_16x16x32_bf16(af, *(const bf16x8*)(wir + kg), aI, 0, 0, 0);
      aG = __builtin_amdgcn_mfma_f32_16x16x32_bf16(af, *(const bf16x8*)(wgr + kg), aG, 0, 0, 0);
      aO = __builtin_amdgcn_mfma_f32_16x16x32_bf16(af, *(const bf16x8*)(wor + kg), aO, 0, 0, 0);
    }
    const int col = wid * 16 + l16;
    const float bfc = bfv[col], bic = biv[col], bgc = bgv[col], boc = bov[col];
    float* cxp = cx_ws + ((size_t)(wg * 16 + wid) * 64 + lane) * 4;  // lane-private
    const float4 cxv = *(const float4*)cxp;
    const float cxa[4] = { cxv.x, cxv.y, cxv.z, cxv.w };
    float h4[4], c4v[4];
    #pragma unroll
    for (int r = 0; r < 4; ++r) {
      const float F = sigm(aF[r] + bfc);
      const float I = sigm(aI[r] + bic);
      const float G = tanhf(aG[r] + bgc);
      const float O = sigm(aO[r] + boc);
      const float c2 = F * cxa[r] + I * G;
      c4v[r] = c2;
      h4[r]  = O * tanhf(c2);
    }
    *(float4*)cxp = make_float4(c4v[0], c4v[1], c4v[2], c4v[3]);
    #pragma unroll
    for (int r = 0; r < 4; ++r)
      s_lds[wid * 256 + (kq * 4 + r) * 16 + l16] = h4[r];
    if (t == SEQ - 1) {
      #pragma unroll
      for (int r = 0; r < 4; ++r)
        out[(size_t)SEQ * 65536 + 65536 + (size_t)(r0 + kq * 4 + r) * 256 + col] = c4v[r];
    }
  }
  __syncthreads();
  // ---- repack h: hx (bf16) + out (f32, row-contiguous)
  {
    const int row = tid >> 6, c4 = (tid & 63) * 4;
    float hv[4];
    #pragma unroll
    for (int e = 0; e < 4; ++e)
      hv[e] = s_lds[((c4 + e) >> 4) * 256 + row * 16 + ((c4 + e) & 15)];
    *(u64*)(hx_ws + (size_t)(r0 + row) * HH + c4) = pack4(hv[0], hv[1], hv[2], hv[3]);
    *(float4*)(out + (size_t)t * 65536 + (size_t)(r0 + row) * 256 + c4) =
        make_float4(hv[0], hv[1], hv[2], hv[3]);
    if (t == SEQ - 1)
      *(float4*)(out + (size_t)SEQ * 65536 + (size_t)(r0 + row) * 256 + c4) =
          make_float4(hv[0], hv[1], hv[2], hv[3]);
  }
}

extern "C" void kernel_launch(void* const* d_in, const int* in_sizes, int n_in,
                              void* d_out, int out_size, void* d_ws, size_t ws_size,
                              hipStream_t stream) {
  const float* x   = (const float*)d_in[0];
  const float* Wq  = (const float*)d_in[1];
  const float* Wk  = (const float*)d_in[2];
  const float* Wv  = (const float*)d_in[3];
  const float* Wf  = (const float*)d_in[4];
  const float* bfv = (const float*)d_in[5];
  const float* Wi  = (const float*)d_in[6];
  const float* biv = (const float*)d_in[7];
  const float* Wgg = (const float*)d_in[8];
  const float* bgv = (const float*)d_in[9];
  const float* Wo  = (const float*)d_in[10];
  const float* bov = (const float*)d_in[11];
  float* out = (float*)d_out;
  char* wsb = (char*)d_ws;

  hipLaunchKernelGGL(qlstm_init_kernel, dim3(512), dim3(256), 0, stream,
                     Wq, Wk, Wv, Wf, Wi, Wgg, Wo, wsb);

  for (int t = 0; t < SEQ; ++t) {
    hipLaunchKernelGGL(qkv_kernel, dim3(384), dim3(256), 0, stream, x, wsb, t);
    hipLaunchKernelGGL(bcde_kernel, dim3(16), dim3(1024), 0, stream,
                       bfv, biv, bgv, bov, out, wsb, t);
  }
}

// Round 12
// 27496.732 us; speedup vs baseline: 2.9082x; 1.3341x over previous
//
#include <hip/hip_runtime.h>
#include <hip/hip_bf16.h>

// QLSTM (S=512,B=256,D=256,H=256,E=512), f32 in/out, bf16 MFMA internals.
// Algebraic refactor: M = Wq^T Wk (E,E), Ug = Wg@Wv (H,E) precomputed once.
//   scores = (comb @ M) @ comb^T ; a2 = P @ comb ; gate_g = a2 @ Ug^T + bg
// -> only cross-WG tensor is comb/combT (double-buffered by step parity).
// ONE kernel per step (64 WGs x 1024 thr = strip s x hquarter q4); kernel
// boundary = grid sync. 513 dispatches total in the graph.
// r12 fix: MT stored TRANSPOSED (MT[n][e] = M[e][n]) so the swapped-operand
// Z step computes comb@M, not comb@M^T (M is not symmetric).

typedef __hip_bfloat16 bf16;
typedef __attribute__((ext_vector_type(8))) short bf16x8;   // 8 bf16 = 4 VGPR
typedef __attribute__((ext_vector_type(4))) float f32x4;
typedef unsigned long long u64;

#define SEQ 512
#define BB  256
#define DD  256
#define HH  256
#define EE  512
#define QK_SCALE 0.04419417382415922f  // 1/sqrt(512)

// ws layout (bytes)
#define WS_COMB0  0          // bf16 [256][512]  step-parity 0
#define WS_COMB1  262144     // parity 1
#define WS_COMBT0 524288     // bf16 [512][256]  comb transposed, parity 0
#define WS_COMBT1 786432     // parity 1
#define WS_CX     1048576    // f32 [64 WG][1024]  lane-stable cell state
#define WS_MT     1310720    // bf16 [512][512]  MT[n][e] = M[e][n], M = Wq^T Wk
#define WS_UF     1835008    // bf16 [256][512]  Uf = Wf @ Wv
#define WS_UI     2097152
#define WS_UG     2359296
#define WS_UO     2621440
#define WS_END    2883584

__device__ __forceinline__ float sigm(float x) { return 1.0f / (1.0f + __expf(-x)); }

__device__ __forceinline__ unsigned short f2bf_s(float f) {
  bf16 h = __float2bfloat16(f);
  return *reinterpret_cast<unsigned short*>(&h);
}
__device__ __forceinline__ u64 pack4(float a, float b, float c, float d) {
  union { unsigned short s[4]; u64 u; } x;
  x.s[0] = f2bf_s(a); x.s[1] = f2bf_s(b); x.s[2] = f2bf_s(c); x.s[3] = f2bf_s(d);
  return x.u;
}

// ---------------- init: comb0/combT0, cx=0, MT, U matrices ------------------
__global__ void __launch_bounds__(256) qlstm_init_kernel(
    const float* __restrict__ x,
    const float* __restrict__ Wq, const float* __restrict__ Wk, const float* __restrict__ Wv,
    const float* __restrict__ Wf, const float* __restrict__ Wi,
    const float* __restrict__ Wg, const float* __restrict__ Wo,
    char* __restrict__ wsb)
{
  const int gid = blockIdx.x * blockDim.x + threadIdx.x;   // 0..131071
  bf16* comb0  = (bf16*)(wsb + WS_COMB0);
  bf16* combT0 = (bf16*)(wsb + WS_COMBT0);
  float* cx    = (float*)(wsb + WS_CX);
  bf16* mt     = (bf16*)(wsb + WS_MT);

  if (gid < 65536) {
    const int i = gid >> 8, e = gid & 255;
    const bf16 xv = __float2bfloat16(x[i * DD + e]);       // x[t=0][i][e]
    comb0[i * EE + e] = xv;
    comb0[i * EE + 256 + e] = __float2bfloat16(0.0f);
    combT0[e * BB + i] = xv;
    combT0[(256 + e) * BB + i] = __float2bfloat16(0.0f);
  } else {
    cx[gid - 65536] = 0.0f;
  }

  // MT[n][e] = M[e][n] = sum_j Wq[j][e] * Wk[j][n]
  // (Z step's swapped-operand MFMA computes D[n][i] = sum_e MT[n][e]*comb[i][e]
  //  = z[i][n] = (comb @ M)[i][n])
  #pragma unroll 1
  for (int kk = 0; kk < 2; ++kk) {
    const int o = gid + kk * 131072;        // 0..262143
    const int n = o >> 9, e = o & 511;
    float acc = 0.0f;
    #pragma unroll 4
    for (int j = 0; j < 512; ++j) acc = __builtin_fmaf(Wq[j * 512 + e], Wk[j * 512 + n], acc);
    mt[o] = __float2bfloat16(acc);
  }
  // U_a[h][e] = sum_e' W_a[h][e'] * Wv[e'][e]
  const float* srcs[4] = { Wf, Wi, Wg, Wo };
  const int offs[4] = { WS_UF, WS_UI, WS_UG, WS_UO };
  #pragma unroll 1
  for (int a = 0; a < 4; ++a) {
    bf16* U = (bf16*)(wsb + offs[a]);
    const float* W = srcs[a];
    const int h = gid >> 9, e = gid & 511;
    float acc = 0.0f;
    #pragma unroll 4
    for (int ep = 0; ep < 512; ++ep) acc = __builtin_fmaf(W[h * 512 + ep], Wv[ep * 512 + e], acc);
    U[gid] = __float2bfloat16(acc);
  }
}

// ---------------- per-step kernel: 64 WGs x 1024 thr ------------------------
__global__ void __launch_bounds__(1024) qlstm_step_kernel(
    const float* __restrict__ x,
    const float* __restrict__ bfv, const float* __restrict__ biv,
    const float* __restrict__ bgv, const float* __restrict__ bov,
    float* __restrict__ out, char* __restrict__ wsb, int t)
{
  const int par = t & 1;
  const bf16* comb   = (const bf16*)(wsb + (par ? WS_COMB1 : WS_COMB0));
  const bf16* combT  = (const bf16*)(wsb + (par ? WS_COMBT1 : WS_COMBT0));
  bf16* combN  = (bf16*)(wsb + (par ? WS_COMB0 : WS_COMB1));
  bf16* combTN = (bf16*)(wsb + (par ? WS_COMBT0 : WS_COMBT1));
  float* cx_ws = (float*)(wsb + WS_CX);
  const bf16* mt   = (const bf16*)(wsb + WS_MT);
  const bf16* uf_b = (const bf16*)(wsb + WS_UF);
  const bf16* ui_b = (const bf16*)(wsb + WS_UI);
  const bf16* ug_b = (const bf16*)(wsb + WS_UG);
  const bf16* uo_b = (const bf16*)(wsb + WS_UO);

  const int wg   = blockIdx.x;     // 0..63
  const int s    = wg >> 2;        // strip 0..15
  const int q4   = wg & 3;         // h-quarter 0..3
  const int r0   = s * 16;
  const int tid  = threadIdx.x;
  const int wid  = tid >> 6;       // wave 0..15
  const int lane = tid & 63;
  const int l16  = lane & 15;
  const int kq   = lane >> 4;      // 0..3

  __shared__ unsigned short z_lds[16 * 520];    // z strip (bf16), batch-major
  __shared__ unsigned short a_lds[16 * 520];    // a2 strip (bf16), batch-major
  __shared__ float          s_lds[16 * 256];    // scores f32
  __shared__ unsigned short p_lds[16 * 264];    // probs bf16 (+8 pad)
  __shared__ float          g_lds[16 * 256];    // gate pre-acts

  // ---- Z: z_strip = comb_strip @ M   (A = MT rows n, B = comb rows i)
  #pragma unroll
  for (int h2 = 0; h2 < 2; ++h2) {
    const int n0 = (wid * 2 + h2) * 16;
    const bf16* arow = mt + (size_t)(n0 + l16) * EE;
    const bf16* brow = comb + (size_t)(r0 + l16) * EE;
    f32x4 acc = {0.f, 0.f, 0.f, 0.f};
    #pragma unroll
    for (int ks = 0; ks < 16; ++ks) {
      const int kg = ks * 32 + kq * 8;
      bf16x8 af = *(const bf16x8*)(arow + kg);
      bf16x8 bf8 = *(const bf16x8*)(brow + kg);
      acc = __builtin_amdgcn_mfma_f32_16x16x32_bf16(af, bf8, acc, 0, 0, 0);
    }
    *(u64*)(&z_lds[l16 * 520 + n0 + kq * 4]) = pack4(acc[0], acc[1], acc[2], acc[3]);
  }
  __syncthreads();
  // ---- B: scores = z_strip @ comb^T  (A = z rows i, B = comb rows j)
  {
    const int j0 = wid * 16;
    const unsigned short* arow = &z_lds[l16 * 520];
    const bf16* brow = comb + (size_t)(j0 + l16) * EE;
    f32x4 acc = {0.f, 0.f, 0.f, 0.f};
    #pragma unroll
    for (int ks = 0; ks < 16; ++ks) {
      const int kg = ks * 32 + kq * 8;
      bf16x8 af = *(const bf16x8*)(arow + kg);
      bf16x8 bf8 = *(const bf16x8*)(brow + kg);
      acc = __builtin_amdgcn_mfma_f32_16x16x32_bf16(af, bf8, acc, 0, 0, 0);
    }
    #pragma unroll
    for (int r = 0; r < 4; ++r)
      s_lds[(kq * 4 + r) * 256 + j0 + l16] = acc[r];
  }
  __syncthreads();
  // ---- C: softmax row i = wid
  {
    const int i = wid;
    const float4 v = *(const float4*)(&s_lds[i * 256 + lane * 4]);
    float m = fmaxf(fmaxf(v.x, v.y), fmaxf(v.z, v.w));
    #pragma unroll
    for (int off = 32; off > 0; off >>= 1) m = fmaxf(m, __shfl_xor(m, off));
    float e0 = __expf((v.x - m) * QK_SCALE);
    float e1 = __expf((v.y - m) * QK_SCALE);
    float e2 = __expf((v.z - m) * QK_SCALE);
    float e3 = __expf((v.w - m) * QK_SCALE);
    float sum = e0 + e1 + e2 + e3;
    #pragma unroll
    for (int off = 32; off > 0; off >>= 1) sum += __shfl_xor(sum, off);
    const float rinv = 1.0f / sum;
    unsigned short* pp = &p_lds[i * 264 + lane * 4];
    pp[0] = f2bf_s(e0 * rinv);
    pp[1] = f2bf_s(e1 * rinv);
    pp[2] = f2bf_s(e2 * rinv);
    pp[3] = f2bf_s(e3 * rinv);
  }
  __syncthreads();
  // ---- D: a2 = P @ comb  (swapped: A = combT rows n, B = P rows i), K=256
  #pragma unroll
  for (int q8 = 0; q8 < 2; ++q8) {
    const int n0 = wid * 16 + q8 * 256;
    const bf16* arow = combT + (size_t)(n0 + l16) * BB;
    const unsigned short* brow = &p_lds[l16 * 264];
    f32x4 acc = {0.f, 0.f, 0.f, 0.f};
    #pragma unroll
    for (int ks = 0; ks < 8; ++ks) {
      const int kg = ks * 32 + kq * 8;
      bf16x8 af = *(const bf16x8*)(arow + kg);
      bf16x8 bf8 = *(const bf16x8*)(brow + kg);
      acc = __builtin_amdgcn_mfma_f32_16x16x32_bf16(af, bf8, acc, 0, 0, 0);
    }
    *(u64*)(&a_lds[l16 * 520 + n0 + kq * 4]) = pack4(acc[0], acc[1], acc[2], acc[3]);
  }
  __syncthreads();
  // ---- E: gates for hcols [q4*64, q4*64+64): wave wid -> gate g=wid>>2, hcb=wid&3
  {
    const int g   = wid >> 2;
    const int hcb = wid & 3;
    const int h0  = q4 * 64 + hcb * 16;
    const bf16* U = (g == 0) ? uf_b : (g == 1) ? ui_b : (g == 2) ? ug_b : uo_b;
    const unsigned short* arow = &a_lds[l16 * 520];
    const bf16* brow = U + (size_t)(h0 + l16) * EE;
    f32x4 acc = {0.f, 0.f, 0.f, 0.f};
    #pragma unroll
    for (int ks = 0; ks < 16; ++ks) {
      const int kg = ks * 32 + kq * 8;
      bf16x8 af = *(const bf16x8*)(arow + kg);
      bf16x8 bf8 = *(const bf16x8*)(brow + kg);
      acc = __builtin_amdgcn_mfma_f32_16x16x32_bf16(af, bf8, acc, 0, 0, 0);
    }
    #pragma unroll
    for (int r = 0; r < 4; ++r)
      g_lds[wid * 256 + (kq * 4 + r) * 16 + l16] = acc[r];
  }
  __syncthreads();
  // ---- update: tid -> (hcb2 = tid>>8, i = (tid>>4)&15, c = tid&15)
  {
    const int hcb2 = tid >> 8;
    const int idx  = tid & 255;
    const int i    = idx >> 4, c = idx & 15;
    const int colg = q4 * 64 + hcb2 * 16 + c;
    const float F = sigm(g_lds[(0 * 4 + hcb2) * 256 + idx] + bfv[colg]);
    const float I = sigm(g_lds[(1 * 4 + hcb2) * 256 + idx] + biv[colg]);
    const float G = tanhf(g_lds[(2 * 4 + hcb2) * 256 + idx] + bgv[colg]);
    const float O = sigm(g_lds[(3 * 4 + hcb2) * 256 + idx] + bov[colg]);
    float* cxp = cx_ws + (size_t)wg * 1024 + tid;
    const float c2 = F * (*cxp) + I * G;
    const float h  = O * tanhf(c2);
    *cxp = c2;
    out[(size_t)t * 65536 + (size_t)(r0 + i) * 256 + colg] = h;
    if (t < SEQ - 1) {
      const bf16 hb = __float2bfloat16(h);
      combN[(size_t)(r0 + i) * EE + 256 + colg] = hb;
      combTN[(size_t)(256 + colg) * BB + r0 + i] = hb;
    } else {
      out[(size_t)SEQ * 65536 + (size_t)(r0 + i) * 256 + colg] = h;           // hx tail
      out[(size_t)SEQ * 65536 + 65536 + (size_t)(r0 + i) * 256 + colg] = c2;  // cx tail
    }
  }
  // ---- x-part of next comb (only q4==0 WG of each strip)
  if (q4 == 0 && t < SEQ - 1) {
    #pragma unroll
    for (int u = 0; u < 4; ++u) {
      const int idx2 = tid * 4 + u;          // 0..4095
      const int i2 = idx2 >> 8, e2 = idx2 & 255;
      const bf16 xv = __float2bfloat16(x[((size_t)(t + 1) * BB + r0 + i2) * DD + e2]);
      combN[(size_t)(r0 + i2) * EE + e2] = xv;
      combTN[(size_t)e2 * BB + r0 + i2] = xv;
    }
  }
}

extern "C" void kernel_launch(void* const* d_in, const int* in_sizes, int n_in,
                              void* d_out, int out_size, void* d_ws, size_t ws_size,
                              hipStream_t stream) {
  const float* x   = (const float*)d_in[0];
  const float* Wq  = (const float*)d_in[1];
  const float* Wk  = (const float*)d_in[2];
  const float* Wv  = (const float*)d_in[3];
  const float* Wf  = (const float*)d_in[4];
  const float* bfv = (const float*)d_in[5];
  const float* Wi  = (const float*)d_in[6];
  const float* biv = (const float*)d_in[7];
  const float* Wgg = (const float*)d_in[8];
  const float* bgv = (const float*)d_in[9];
  const float* Wo  = (const float*)d_in[10];
  const float* bov = (const float*)d_in[11];
  float* out = (float*)d_out;
  char* wsb = (char*)d_ws;

  hipLaunchKernelGGL(qlstm_init_kernel, dim3(512), dim3(256), 0, stream,
                     x, Wq, Wk, Wv, Wf, Wi, Wgg, Wo, wsb);

  for (int t = 0; t < SEQ; ++t) {
    hipLaunchKernelGGL(qlstm_step_kernel, dim3(64), dim3(1024), 0, stream,
                       x, bfv, biv, bgv, bov, out, wsb, t);
  }
}

// Round 13
// 22256.812 us; speedup vs baseline: 3.5928x; 1.2354x over previous
//
#include <hip/hip_runtime.h>
#include <hip/hip_bf16.h>

// QLSTM (S=512,B=256,D=256,H=256,E=512), f32 in/out, bf16 MFMA internals.
// Algebraic form: M = Wq^T Wk, U_a = W_a @ Wv precomputed once (init).
//   scores = (comb @ M) @ comb^T ; a2 = P @ comb ; gate_a = a2 @ U_a^T + b_a
// ONE kernel per step (64 WGs x 1024 thr = strip s x hquarter q4); kernel
// boundary = grid sync + coherence. 513 dispatches total.
// r13: explicit 8-deep load batching in Z/B/D/E streams + comb strip staged
// to LDS (breaks load->mfma serialization; math bit-identical to r12).

typedef __hip_bfloat16 bf16;
typedef __attribute__((ext_vector_type(8))) short bf16x8;   // 8 bf16 = 4 VGPR
typedef __attribute__((ext_vector_type(4))) float f32x4;
typedef unsigned long long u64;

#define SEQ 512
#define BB  256
#define DD  256
#define HH  256
#define EE  512
#define QK_SCALE 0.04419417382415922f  // 1/sqrt(512)

// ws layout (bytes)
#define WS_COMB0  0          // bf16 [256][512]  step-parity 0
#define WS_COMB1  262144     // parity 1
#define WS_COMBT0 524288     // bf16 [512][256]  comb transposed, parity 0
#define WS_COMBT1 786432     // parity 1
#define WS_CX     1048576    // f32 [64 WG][1024]  lane-stable cell state
#define WS_MT     1310720    // bf16 [512][512]  MT[n][e] = M[e][n], M = Wq^T Wk
#define WS_UF     1835008    // bf16 [256][512]  Uf = Wf @ Wv
#define WS_UI     2097152
#define WS_UG     2359296
#define WS_UO     2621440
#define WS_END    2883584

__device__ __forceinline__ float sigm(float x) { return 1.0f / (1.0f + __expf(-x)); }

__device__ __forceinline__ unsigned short f2bf_s(float f) {
  bf16 h = __float2bfloat16(f);
  return *reinterpret_cast<unsigned short*>(&h);
}
__device__ __forceinline__ u64 pack4(float a, float b, float c, float d) {
  union { unsigned short s[4]; u64 u; } x;
  x.s[0] = f2bf_s(a); x.s[1] = f2bf_s(b); x.s[2] = f2bf_s(c); x.s[3] = f2bf_s(d);
  return x.u;
}

// ---------------- init: comb0/combT0, cx=0, MT, U matrices ------------------
__global__ void __launch_bounds__(256) qlstm_init_kernel(
    const float* __restrict__ x,
    const float* __restrict__ Wq, const float* __restrict__ Wk, const float* __restrict__ Wv,
    const float* __restrict__ Wf, const float* __restrict__ Wi,
    const float* __restrict__ Wg, const float* __restrict__ Wo,
    char* __restrict__ wsb)
{
  const int gid = blockIdx.x * blockDim.x + threadIdx.x;   // 0..131071
  bf16* comb0  = (bf16*)(wsb + WS_COMB0);
  bf16* combT0 = (bf16*)(wsb + WS_COMBT0);
  float* cx    = (float*)(wsb + WS_CX);
  bf16* mt     = (bf16*)(wsb + WS_MT);

  if (gid < 65536) {
    const int i = gid >> 8, e = gid & 255;
    const bf16 xv = __float2bfloat16(x[i * DD + e]);       // x[t=0][i][e]
    comb0[i * EE + e] = xv;
    comb0[i * EE + 256 + e] = __float2bfloat16(0.0f);
    combT0[e * BB + i] = xv;
    combT0[(256 + e) * BB + i] = __float2bfloat16(0.0f);
  } else {
    cx[gid - 65536] = 0.0f;
  }

  // MT[n][e] = M[e][n] = sum_j Wq[j][e] * Wk[j][n]
  #pragma unroll 1
  for (int kk = 0; kk < 2; ++kk) {
    const int o = gid + kk * 131072;        // 0..262143
    const int n = o >> 9, e = o & 511;
    float acc = 0.0f;
    #pragma unroll 4
    for (int j = 0; j < 512; ++j) acc = __builtin_fmaf(Wq[j * 512 + e], Wk[j * 512 + n], acc);
    mt[o] = __float2bfloat16(acc);
  }
  // U_a[h][e] = sum_e' W_a[h][e'] * Wv[e'][e]
  const float* srcs[4] = { Wf, Wi, Wg, Wo };
  const int offs[4] = { WS_UF, WS_UI, WS_UG, WS_UO };
  #pragma unroll 1
  for (int a = 0; a < 4; ++a) {
    bf16* U = (bf16*)(wsb + offs[a]);
    const float* W = srcs[a];
    const int h = gid >> 9, e = gid & 511;
    float acc = 0.0f;
    #pragma unroll 4
    for (int ep = 0; ep < 512; ++ep) acc = __builtin_fmaf(W[h * 512 + ep], Wv[ep * 512 + e], acc);
    U[gid] = __float2bfloat16(acc);
  }
}

// ---------------- per-step kernel: 64 WGs x 1024 thr ------------------------
__global__ void __launch_bounds__(1024) qlstm_step_kernel(
    const float* __restrict__ x,
    const float* __restrict__ bfv, const float* __restrict__ biv,
    const float* __restrict__ bgv, const float* __restrict__ bov,
    float* __restrict__ out, char* __restrict__ wsb, int t)
{
  const int par = t & 1;
  const bf16* comb   = (const bf16*)(wsb + (par ? WS_COMB1 : WS_COMB0));
  const bf16* combT  = (const bf16*)(wsb + (par ? WS_COMBT1 : WS_COMBT0));
  bf16* combN  = (bf16*)(wsb + (par ? WS_COMB0 : WS_COMB1));
  bf16* combTN = (bf16*)(wsb + (par ? WS_COMBT0 : WS_COMBT1));
  float* cx_ws = (float*)(wsb + WS_CX);
  const bf16* mt   = (const bf16*)(wsb + WS_MT);
  const bf16* uf_b = (const bf16*)(wsb + WS_UF);
  const bf16* ui_b = (const bf16*)(wsb + WS_UI);
  const bf16* ug_b = (const bf16*)(wsb + WS_UG);
  const bf16* uo_b = (const bf16*)(wsb + WS_UO);

  const int wg   = blockIdx.x;     // 0..63
  const int s    = wg >> 2;        // strip 0..15
  const int q4   = wg & 3;         // h-quarter 0..3
  const int r0   = s * 16;
  const int tid  = threadIdx.x;
  const int wid  = tid >> 6;       // wave 0..15
  const int lane = tid & 63;
  const int l16  = lane & 15;
  const int kq   = lane >> 4;      // 0..3

  __shared__ unsigned short c_lds[16 * 520];    // comb strip rows (staged)
  __shared__ unsigned short z_lds[16 * 520];    // z strip (bf16), batch-major
  __shared__ unsigned short a_lds[16 * 520];    // a2 strip (bf16), batch-major
  __shared__ float          s_lds[16 * 256];    // scores f32
  __shared__ unsigned short p_lds[16 * 264];    // probs bf16 (+8 pad)
  __shared__ float          g_lds[16 * 256];    // gate pre-acts

  // ---- stage comb strip rows r0..r0+16 into LDS (16KB, one pass)
  {
    const int row = tid >> 6, c8 = (tid & 63) * 8;
    *(bf16x8*)(&c_lds[row * 520 + c8]) =
        *(const bf16x8*)(comb + (size_t)(r0 + row) * EE + c8);
  }
  __syncthreads();

  // ---- Z: z_strip = comb_strip @ M   (A = MT rows n [8-deep batch], B = LDS)
  #pragma unroll
  for (int h2 = 0; h2 < 2; ++h2) {
    const int n0 = (wid * 2 + h2) * 16;
    const bf16* arow = mt + (size_t)(n0 + l16) * EE;
    const unsigned short* brow = &c_lds[l16 * 520];
    f32x4 acc = {0.f, 0.f, 0.f, 0.f};
    #pragma unroll
    for (int half = 0; half < 2; ++half) {
      bf16x8 mfr[8];
      #pragma unroll
      for (int u = 0; u < 8; ++u)
        mfr[u] = *(const bf16x8*)(arow + (half * 8 + u) * 32 + kq * 8);
      #pragma unroll
      for (int u = 0; u < 8; ++u) {
        bf16x8 bf8 = *(const bf16x8*)(brow + (half * 8 + u) * 32 + kq * 8);
        acc = __builtin_amdgcn_mfma_f32_16x16x32_bf16(mfr[u], bf8, acc, 0, 0, 0);
      }
    }
    *(u64*)(&z_lds[l16 * 520 + n0 + kq * 4]) = pack4(acc[0], acc[1], acc[2], acc[3]);
  }
  __syncthreads();
  // ---- B: scores = z_strip @ comb^T  (A = z LDS, B = comb rows j [batched])
  {
    const int j0 = wid * 16;
    const unsigned short* arow = &z_lds[l16 * 520];
    const bf16* brow = comb + (size_t)(j0 + l16) * EE;
    f32x4 acc = {0.f, 0.f, 0.f, 0.f};
    #pragma unroll
    for (int half = 0; half < 2; ++half) {
      bf16x8 cfr[8];
      #pragma unroll
      for (int u = 0; u < 8; ++u)
        cfr[u] = *(const bf16x8*)(brow + (half * 8 + u) * 32 + kq * 8);
      #pragma unroll
      for (int u = 0; u < 8; ++u) {
        bf16x8 af = *(const bf16x8*)(arow + (half * 8 + u) * 32 + kq * 8);
        acc = __builtin_amdgcn_mfma_f32_16x16x32_bf16(af, cfr[u], acc, 0, 0, 0);
      }
    }
    #pragma unroll
    for (int r = 0; r < 4; ++r)
      s_lds[(kq * 4 + r) * 256 + j0 + l16] = acc[r];
  }
  __syncthreads();
  // ---- C: softmax row i = wid
  {
    const int i = wid;
    const float4 v = *(const float4*)(&s_lds[i * 256 + lane * 4]);
    float m = fmaxf(fmaxf(v.x, v.y), fmaxf(v.z, v.w));
    #pragma unroll
    for (int off = 32; off > 0; off >>= 1) m = fmaxf(m, __shfl_xor(m, off));
    float e0 = __expf((v.x - m) * QK_SCALE);
    float e1 = __expf((v.y - m) * QK_SCALE);
    float e2 = __expf((v.z - m) * QK_SCALE);
    float e3 = __expf((v.w - m) * QK_SCALE);
    float sum = e0 + e1 + e2 + e3;
    #pragma unroll
    for (int off = 32; off > 0; off >>= 1) sum += __shfl_xor(sum, off);
    const float rinv = 1.0f / sum;
    unsigned short* pp = &p_lds[i * 264 + lane * 4];
    pp[0] = f2bf_s(e0 * rinv);
    pp[1] = f2bf_s(e1 * rinv);
    pp[2] = f2bf_s(e2 * rinv);
    pp[3] = f2bf_s(e3 * rinv);
  }
  __syncthreads();
  // ---- D: a2 = P @ comb  (A = combT rows n [batched], B = P LDS), K=256
  #pragma unroll
  for (int q8 = 0; q8 < 2; ++q8) {
    const int n0 = wid * 16 + q8 * 256;
    const bf16* arow = combT + (size_t)(n0 + l16) * BB;
    const unsigned short* brow = &p_lds[l16 * 264];
    f32x4 acc = {0.f, 0.f, 0.f, 0.f};
    bf16x8 tfr[8];
    #pragma unroll
    for (int u = 0; u < 8; ++u)
      tfr[u] = *(const bf16x8*)(arow + u * 32 + kq * 8);
    #pragma unroll
    for (int u = 0; u < 8; ++u) {
      bf16x8 bf8 = *(const bf16x8*)(brow + u * 32 + kq * 8);
      acc = __builtin_amdgcn_mfma_f32_16x16x32_bf16(tfr[u], bf8, acc, 0, 0, 0);
    }
    *(u64*)(&a_lds[l16 * 520 + n0 + kq * 4]) = pack4(acc[0], acc[1], acc[2], acc[3]);
  }
  __syncthreads();
  // ---- E: gates for hcols [q4*64, q4*64+64): wave wid -> gate g=wid>>2, hcb=wid&3
  {
    const int g   = wid >> 2;
    const int hcb = wid & 3;
    const int h0  = q4 * 64 + hcb * 16;
    const bf16* U = (g == 0) ? uf_b : (g == 1) ? ui_b : (g == 2) ? ug_b : uo_b;
    const unsigned short* arow = &a_lds[l16 * 520];
    const bf16* brow = U + (size_t)(h0 + l16) * EE;
    f32x4 acc = {0.f, 0.f, 0.f, 0.f};
    #pragma unroll
    for (int half = 0; half < 2; ++half) {
      bf16x8 ufr[8];
      #pragma unroll
      for (int u = 0; u < 8; ++u)
        ufr[u] = *(const bf16x8*)(brow + (half * 8 + u) * 32 + kq * 8);
      #pragma unroll
      for (int u = 0; u < 8; ++u) {
        bf16x8 af = *(const bf16x8*)(arow + (half * 8 + u) * 32 + kq * 8);
        acc = __builtin_amdgcn_mfma_f32_16x16x32_bf16(af, ufr[u], acc, 0, 0, 0);
      }
    }
    #pragma unroll
    for (int r = 0; r < 4; ++r)
      g_lds[wid * 256 + (kq * 4 + r) * 16 + l16] = acc[r];
  }
  __syncthreads();
  // ---- update: tid -> (hcb2 = tid>>8, i = (tid>>4)&15, c = tid&15)
  {
    const int hcb2 = tid >> 8;
    const int idx  = tid & 255;
    const int i    = idx >> 4, c = idx & 15;
    const int colg = q4 * 64 + hcb2 * 16 + c;
    const float F = sigm(g_lds[(0 * 4 + hcb2) * 256 + idx] + bfv[colg]);
    const float I = sigm(g_lds[(1 * 4 + hcb2) * 256 + idx] + biv[colg]);
    const float G = tanhf(g_lds[(2 * 4 + hcb2) * 256 + idx] + bgv[colg]);
    const float O = sigm(g_lds[(3 * 4 + hcb2) * 256 + idx] + bov[colg]);
    float* cxp = cx_ws + (size_t)wg * 1024 + tid;
    const float c2 = F * (*cxp) + I * G;
    const float h  = O * tanhf(c2);
    *cxp = c2;
    out[(size_t)t * 65536 + (size_t)(r0 + i) * 256 + colg] = h;
    if (t < SEQ - 1) {
      const bf16 hb = __float2bfloat16(h);
      combN[(size_t)(r0 + i) * EE + 256 + colg] = hb;
      combTN[(size_t)(256 + colg) * BB + r0 + i] = hb;
    } else {
      out[(size_t)SEQ * 65536 + (size_t)(r0 + i) * 256 + colg] = h;           // hx tail
      out[(size_t)SEQ * 65536 + 65536 + (size_t)(r0 + i) * 256 + colg] = c2;  // cx tail
    }
  }
  // ---- x-part of next comb (only q4==0 WG of each strip)
  if (q4 == 0 && t < SEQ - 1) {
    #pragma unroll
    for (int u = 0; u < 4; ++u) {
      const int idx2 = tid * 4 + u;          // 0..4095
      const int i2 = idx2 >> 8, e2 = idx2 & 255;
      const bf16 xv = __float2bfloat16(x[((size_t)(t + 1) * BB + r0 + i2) * DD + e2]);
      combN[(size_t)(r0 + i2) * EE + e2] = xv;
      combTN[(size_t)e2 * BB + r0 + i2] = xv;
    }
  }
}

extern "C" void kernel_launch(void* const* d_in, const int* in_sizes, int n_in,
                              void* d_out, int out_size, void* d_ws, size_t ws_size,
                              hipStream_t stream) {
  const float* x   = (const float*)d_in[0];
  const float* Wq  = (const float*)d_in[1];
  const float* Wk  = (const float*)d_in[2];
  const float* Wv  = (const float*)d_in[3];
  const float* Wf  = (const float*)d_in[4];
  const float* bfv = (const float*)d_in[5];
  const float* Wi  = (const float*)d_in[6];
  const float* biv = (const float*)d_in[7];
  const float* Wgg = (const float*)d_in[8];
  const float* bgv = (const float*)d_in[9];
  const float* Wo  = (const float*)d_in[10];
  const float* bov = (const float*)d_in[11];
  float* out = (float*)d_out;
  char* wsb = (char*)d_ws;

  hipLaunchKernelGGL(qlstm_init_kernel, dim3(512), dim3(256), 0, stream,
                     x, Wq, Wk, Wv, Wf, Wi, Wgg, Wo, wsb);

  for (int t = 0; t < SEQ; ++t) {
    hipLaunchKernelGGL(qlstm_step_kernel, dim3(64), dim3(1024), 0, stream,
                       x, bfv, biv, bgv, bov, out, wsb, t);
  }
}

// Round 14
// 20869.438 us; speedup vs baseline: 3.8317x; 1.0665x over previous
//
#include <hip/hip_runtime.h>
#include <hip/hip_bf16.h>

// QLSTM (S=512,B=256,D=256,H=256,E=512), f32 in/out, bf16 MFMA internals.
// Algebraic form: M = Wq^T Wk, U_a = W_a @ Wv precomputed once (init).
//   scores = (comb @ M) @ comb^T ; a2 = P @ comb ; gate_a = a2 @ U_a^T + b_a
// ONE kernel per step (64 WGs x 1024 thr = strip s x hquarter q4); kernel
// boundary = grid sync + coherence. 513 dispatches total.
// r13: 8-deep load batching in Z/B/D/E + comb strip staged to LDS.
// r14: ALL cross-step stores coalesced — combT written via LDS-transposed
//      16B segments (was 2B scatter across 2048 falsely-shared lines).

typedef __hip_bfloat16 bf16;
typedef __attribute__((ext_vector_type(8))) short bf16x8;   // 8 bf16 = 4 VGPR
typedef __attribute__((ext_vector_type(4))) float f32x4;
typedef unsigned long long u64;

#define SEQ 512
#define BB  256
#define DD  256
#define HH  256
#define EE  512
#define QK_SCALE 0.04419417382415922f  // 1/sqrt(512)

// ws layout (bytes)
#define WS_COMB0  0          // bf16 [256][512]  step-parity 0
#define WS_COMB1  262144     // parity 1
#define WS_COMBT0 524288     // bf16 [512][256]  comb transposed, parity 0
#define WS_COMBT1 786432     // parity 1
#define WS_CX     1048576    // f32 [64 WG][1024]  lane-stable cell state
#define WS_MT     1310720    // bf16 [512][512]  MT[n][e] = M[e][n], M = Wq^T Wk
#define WS_UF     1835008    // bf16 [256][512]  Uf = Wf @ Wv
#define WS_UI     2097152
#define WS_UG     2359296
#define WS_UO     2621440
#define WS_END    2883584

__device__ __forceinline__ float sigm(float x) { return 1.0f / (1.0f + __expf(-x)); }

__device__ __forceinline__ unsigned short f2bf_s(float f) {
  bf16 h = __float2bfloat16(f);
  return *reinterpret_cast<unsigned short*>(&h);
}
__device__ __forceinline__ u64 pack4(float a, float b, float c, float d) {
  union { unsigned short s[4]; u64 u; } x;
  x.s[0] = f2bf_s(a); x.s[1] = f2bf_s(b); x.s[2] = f2bf_s(c); x.s[3] = f2bf_s(d);
  return x.u;
}

// ---------------- init: comb0/combT0, cx=0, MT, U matrices ------------------
__global__ void __launch_bounds__(256) qlstm_init_kernel(
    const float* __restrict__ x,
    const float* __restrict__ Wq, const float* __restrict__ Wk, const float* __restrict__ Wv,
    const float* __restrict__ Wf, const float* __restrict__ Wi,
    const float* __restrict__ Wg, const float* __restrict__ Wo,
    char* __restrict__ wsb)
{
  const int gid = blockIdx.x * blockDim.x + threadIdx.x;   // 0..131071
  bf16* comb0  = (bf16*)(wsb + WS_COMB0);
  bf16* combT0 = (bf16*)(wsb + WS_COMBT0);
  float* cx    = (float*)(wsb + WS_CX);
  bf16* mt     = (bf16*)(wsb + WS_MT);

  if (gid < 65536) {
    const int i = gid >> 8, e = gid & 255;
    const bf16 xv = __float2bfloat16(x[i * DD + e]);       // x[t=0][i][e]
    comb0[i * EE + e] = xv;
    comb0[i * EE + 256 + e] = __float2bfloat16(0.0f);
    combT0[e * BB + i] = xv;
    combT0[(256 + e) * BB + i] = __float2bfloat16(0.0f);
  } else {
    cx[gid - 65536] = 0.0f;
  }

  // MT[n][e] = M[e][n] = sum_j Wq[j][e] * Wk[j][n]
  #pragma unroll 1
  for (int kk = 0; kk < 2; ++kk) {
    const int o = gid + kk * 131072;        // 0..262143
    const int n = o >> 9, e = o & 511;
    float acc = 0.0f;
    #pragma unroll 4
    for (int j = 0; j < 512; ++j) acc = __builtin_fmaf(Wq[j * 512 + e], Wk[j * 512 + n], acc);
    mt[o] = __float2bfloat16(acc);
  }
  // U_a[h][e] = sum_e' W_a[h][e'] * Wv[e'][e]
  const float* srcs[4] = { Wf, Wi, Wg, Wo };
  const int offs[4] = { WS_UF, WS_UI, WS_UG, WS_UO };
  #pragma unroll 1
  for (int a = 0; a < 4; ++a) {
    bf16* U = (bf16*)(wsb + offs[a]);
    const float* W = srcs[a];
    const int h = gid >> 9, e = gid & 511;
    float acc = 0.0f;
    #pragma unroll 4
    for (int ep = 0; ep < 512; ++ep) acc = __builtin_fmaf(W[h * 512 + ep], Wv[ep * 512 + e], acc);
    U[gid] = __float2bfloat16(acc);
  }
}

// ---------------- per-step kernel: 64 WGs x 1024 thr ------------------------
__global__ void __launch_bounds__(1024) qlstm_step_kernel(
    const float* __restrict__ x,
    const float* __restrict__ bfv, const float* __restrict__ biv,
    const float* __restrict__ bgv, const float* __restrict__ bov,
    float* __restrict__ out, char* __restrict__ wsb, int t)
{
  const int par = t & 1;
  const bf16* comb   = (const bf16*)(wsb + (par ? WS_COMB1 : WS_COMB0));
  const bf16* combT  = (const bf16*)(wsb + (par ? WS_COMBT1 : WS_COMBT0));
  bf16* combN  = (bf16*)(wsb + (par ? WS_COMB0 : WS_COMB1));
  bf16* combTN = (bf16*)(wsb + (par ? WS_COMBT0 : WS_COMBT1));
  float* cx_ws = (float*)(wsb + WS_CX);
  const bf16* mt   = (const bf16*)(wsb + WS_MT);
  const bf16* uf_b = (const bf16*)(wsb + WS_UF);
  const bf16* ui_b = (const bf16*)(wsb + WS_UI);
  const bf16* ug_b = (const bf16*)(wsb + WS_UG);
  const bf16* uo_b = (const bf16*)(wsb + WS_UO);

  const int wg   = blockIdx.x;     // 0..63
  const int s    = wg >> 2;        // strip 0..15
  const int q4   = wg & 3;         // h-quarter 0..3
  const int r0   = s * 16;
  const int tid  = threadIdx.x;
  const int wid  = tid >> 6;       // wave 0..15
  const int lane = tid & 63;
  const int l16  = lane & 15;
  const int kq   = lane >> 4;      // 0..3

  __shared__ unsigned short c_lds[16 * 520];    // comb strip (staged); later xT
  __shared__ unsigned short z_lds[16 * 520];    // z strip (bf16), batch-major
  __shared__ unsigned short a_lds[16 * 520];    // a2 strip (bf16), batch-major
  __shared__ float          s_lds[16 * 256];    // scores f32
  __shared__ unsigned short p_lds[16 * 264];    // probs bf16 (+8 pad)
  __shared__ float          g_lds[16 * 256];    // gate pre-acts
  __shared__ unsigned short ht_lds[64 * 18];    // h tile transposed [colg64][i]

  // ---- stage comb strip rows r0..r0+16 into LDS (16KB, one pass)
  {
    const int row = tid >> 6, c8 = (tid & 63) * 8;
    *(bf16x8*)(&c_lds[row * 520 + c8]) =
        *(const bf16x8*)(comb + (size_t)(r0 + row) * EE + c8);
  }
  __syncthreads();

  // ---- Z: z_strip = comb_strip @ M   (A = MT rows n [8-deep batch], B = LDS)
  #pragma unroll
  for (int h2 = 0; h2 < 2; ++h2) {
    const int n0 = (wid * 2 + h2) * 16;
    const bf16* arow = mt + (size_t)(n0 + l16) * EE;
    const unsigned short* brow = &c_lds[l16 * 520];
    f32x4 acc = {0.f, 0.f, 0.f, 0.f};
    #pragma unroll
    for (int half = 0; half < 2; ++half) {
      bf16x8 mfr[8];
      #pragma unroll
      for (int u = 0; u < 8; ++u)
        mfr[u] = *(const bf16x8*)(arow + (half * 8 + u) * 32 + kq * 8);
      #pragma unroll
      for (int u = 0; u < 8; ++u) {
        bf16x8 bf8 = *(const bf16x8*)(brow + (half * 8 + u) * 32 + kq * 8);
        acc = __builtin_amdgcn_mfma_f32_16x16x32_bf16(mfr[u], bf8, acc, 0, 0, 0);
      }
    }
    *(u64*)(&z_lds[l16 * 520 + n0 + kq * 4]) = pack4(acc[0], acc[1], acc[2], acc[3]);
  }
  __syncthreads();
  // ---- B: scores = z_strip @ comb^T  (A = z LDS, B = comb rows j [batched])
  {
    const int j0 = wid * 16;
    const unsigned short* arow = &z_lds[l16 * 520];
    const bf16* brow = comb + (size_t)(j0 + l16) * EE;
    f32x4 acc = {0.f, 0.f, 0.f, 0.f};
    #pragma unroll
    for (int half = 0; half < 2; ++half) {
      bf16x8 cfr[8];
      #pragma unroll
      for (int u = 0; u < 8; ++u)
        cfr[u] = *(const bf16x8*)(brow + (half * 8 + u) * 32 + kq * 8);
      #pragma unroll
      for (int u = 0; u < 8; ++u) {
        bf16x8 af = *(const bf16x8*)(arow + (half * 8 + u) * 32 + kq * 8);
        acc = __builtin_amdgcn_mfma_f32_16x16x32_bf16(af, cfr[u], acc, 0, 0, 0);
      }
    }
    #pragma unroll
    for (int r = 0; r < 4; ++r)
      s_lds[(kq * 4 + r) * 256 + j0 + l16] = acc[r];
  }
  __syncthreads();
  // ---- C: softmax row i = wid
  {
    const int i = wid;
    const float4 v = *(const float4*)(&s_lds[i * 256 + lane * 4]);
    float m = fmaxf(fmaxf(v.x, v.y), fmaxf(v.z, v.w));
    #pragma unroll
    for (int off = 32; off > 0; off >>= 1) m = fmaxf(m, __shfl_xor(m, off));
    float e0 = __expf((v.x - m) * QK_SCALE);
    float e1 = __expf((v.y - m) * QK_SCALE);
    float e2 = __expf((v.z - m) * QK_SCALE);
    float e3 = __expf((v.w - m) * QK_SCALE);
    float sum = e0 + e1 + e2 + e3;
    #pragma unroll
    for (int off = 32; off > 0; off >>= 1) sum += __shfl_xor(sum, off);
    const float rinv = 1.0f / sum;
    unsigned short* pp = &p_lds[i * 264 + lane * 4];
    pp[0] = f2bf_s(e0 * rinv);
    pp[1] = f2bf_s(e1 * rinv);
    pp[2] = f2bf_s(e2 * rinv);
    pp[3] = f2bf_s(e3 * rinv);
  }
  __syncthreads();
  // ---- D: a2 = P @ comb  (A = combT rows n [batched], B = P LDS), K=256
  #pragma unroll
  for (int q8 = 0; q8 < 2; ++q8) {
    const int n0 = wid * 16 + q8 * 256;
    const bf16* arow = combT + (size_t)(n0 + l16) * BB;
    const unsigned short* brow = &p_lds[l16 * 264];
    f32x4 acc = {0.f, 0.f, 0.f, 0.f};
    bf16x8 tfr[8];
    #pragma unroll
    for (int u = 0; u < 8; ++u)
      tfr[u] = *(const bf16x8*)(arow + u * 32 + kq * 8);
    #pragma unroll
    for (int u = 0; u < 8; ++u) {
      bf16x8 bf8 = *(const bf16x8*)(brow + u * 32 + kq * 8);
      acc = __builtin_amdgcn_mfma_f32_16x16x32_bf16(tfr[u], bf8, acc, 0, 0, 0);
    }
    *(u64*)(&a_lds[l16 * 520 + n0 + kq * 4]) = pack4(acc[0], acc[1], acc[2], acc[3]);
  }
  __syncthreads();
  // ---- E: gates for hcols [q4*64, q4*64+64): wave wid -> gate g=wid>>2, hcb=wid&3
  {
    const int g   = wid >> 2;
    const int hcb = wid & 3;
    const int h0  = q4 * 64 + hcb * 16;
    const bf16* U = (g == 0) ? uf_b : (g == 1) ? ui_b : (g == 2) ? ug_b : uo_b;
    const unsigned short* arow = &a_lds[l16 * 520];
    const bf16* brow = U + (size_t)(h0 + l16) * EE;
    f32x4 acc = {0.f, 0.f, 0.f, 0.f};
    #pragma unroll
    for (int half = 0; half < 2; ++half) {
      bf16x8 ufr[8];
      #pragma unroll
      for (int u = 0; u < 8; ++u)
        ufr[u] = *(const bf16x8*)(brow + (half * 8 + u) * 32 + kq * 8);
      #pragma unroll
      for (int u = 0; u < 8; ++u) {
        bf16x8 af = *(const bf16x8*)(arow + (half * 8 + u) * 32 + kq * 8);
        acc = __builtin_amdgcn_mfma_f32_16x16x32_bf16(af, ufr[u], acc, 0, 0, 0);
      }
    }
    #pragma unroll
    for (int r = 0; r < 4; ++r)
      g_lds[wid * 256 + (kq * 4 + r) * 16 + l16] = acc[r];
  }
  __syncthreads();
  // ---- update: tid -> (hcb2 = tid>>8, i = (tid>>4)&15, c = tid&15)
  {
    const int hcb2 = tid >> 8;
    const int idx  = tid & 255;
    const int i    = idx >> 4, c = idx & 15;
    const int colg = q4 * 64 + hcb2 * 16 + c;
    const float F = sigm(g_lds[(0 * 4 + hcb2) * 256 + idx] + bfv[colg]);
    const float I = sigm(g_lds[(1 * 4 + hcb2) * 256 + idx] + biv[colg]);
    const float G = tanhf(g_lds[(2 * 4 + hcb2) * 256 + idx] + bgv[colg]);
    const float O = sigm(g_lds[(3 * 4 + hcb2) * 256 + idx] + bov[colg]);
    float* cxp = cx_ws + (size_t)wg * 1024 + tid;
    const float c2 = F * (*cxp) + I * G;
    const float h  = O * tanhf(c2);
    *cxp = c2;
    out[(size_t)t * 65536 + (size_t)(r0 + i) * 256 + colg] = h;
    const bf16 hb = __float2bfloat16(h);
    if (t < SEQ - 1) {
      combN[(size_t)(r0 + i) * EE + 256 + colg] = hb;   // row-major, coalesced
      ht_lds[(hcb2 * 16 + c) * 18 + i] = *reinterpret_cast<const unsigned short*>(&hb);
    } else {
      out[(size_t)SEQ * 65536 + (size_t)(r0 + i) * 256 + colg] = h;           // hx tail
      out[(size_t)SEQ * 65536 + 65536 + (size_t)(r0 + i) * 256 + colg] = c2;  // cx tail
    }
  }
  __syncthreads();
  if (t < SEQ - 1) {
    // ---- combT h-part: 64 rows x 2 x 16B coalesced segments
    if (tid < 128) {
      const int row64 = tid >> 1, half = tid & 1;
      const int e = 256 + q4 * 64 + row64;
      *(u64*)(combTN + (size_t)e * BB + r0 + half * 8) =
          *(const u64*)(&ht_lds[row64 * 18 + half * 8]);
      *(u64*)(combTN + (size_t)e * BB + r0 + half * 8 + 4) =
          *(const u64*)(&ht_lds[row64 * 18 + half * 8 + 4]);
    }
    // ---- x-part of next comb (q4==0 WGs; uniform branch per WG)
    if (q4 == 0) {
      unsigned short* xT = c_lds;              // reuse, stride 18: [256][18]
      {
        const int i2 = tid >> 6, e4 = (tid & 63) * 4;
        const float4 xf = *(const float4*)(x + ((size_t)(t + 1) * BB + r0 + i2) * DD + e4);
        const u64 p = pack4(xf.x, xf.y, xf.z, xf.w);
        const unsigned short* ps = (const unsigned short*)&p;
        xT[(e4 + 0) * 18 + i2] = ps[0];
        xT[(e4 + 1) * 18 + i2] = ps[1];
        xT[(e4 + 2) * 18 + i2] = ps[2];
        xT[(e4 + 3) * 18 + i2] = ps[3];
        // row-major x part (coalesced): comb[(r0+i2)][e4..e4+4]
        *(u64*)(combN + (size_t)(r0 + i2) * EE + e4) = p;
      }
      __syncthreads();
      if (tid < 512) {
        const int row = tid >> 1, half = tid & 1;
        *(u64*)(combTN + (size_t)row * BB + r0 + half * 8) =
            *(const u64*)(&xT[row * 18 + half * 8]);
        *(u64*)(combTN + (size_t)row * BB + r0 + half * 8 + 4) =
            *(const u64*)(&xT[row * 18 + half * 8 + 4]);
      }
    }
  }
}

extern "C" void kernel_launch(void* const* d_in, const int* in_sizes, int n_in,
                              void* d_out, int out_size, void* d_ws, size_t ws_size,
                              hipStream_t stream) {
  const float* x   = (const float*)d_in[0];
  const float* Wq  = (const float*)d_in[1];
  const float* Wk  = (const float*)d_in[2];
  const float* Wv  = (const float*)d_in[3];
  const float* Wf  = (const float*)d_in[4];
  const float* bfv = (const float*)d_in[5];
  const float* Wi  = (const float*)d_in[6];
  const float* biv = (const float*)d_in[7];
  const float* Wgg = (const float*)d_in[8];
  const float* bgv = (const float*)d_in[9];
  const float* Wo  = (const float*)d_in[10];
  const float* bov = (const float*)d_in[11];
  float* out = (float*)d_out;
  char* wsb = (char*)d_ws;

  hipLaunchKernelGGL(qlstm_init_kernel, dim3(512), dim3(256), 0, stream,
                     x, Wq, Wk, Wv, Wf, Wi, Wgg, Wo, wsb);

  for (int t = 0; t < SEQ; ++t) {
    hipLaunchKernelGGL(qlstm_step_kernel, dim3(64), dim3(1024), 0, stream,
                       x, bfv, biv, bgv, bov, out, wsb, t);
  }
}